// Round 3
// baseline (11195.271 us; speedup 1.0000x reference)
//
#include <hip/hip_runtime.h>
#include <hip/hip_cooperative_groups.h>
#include <cstdint>
#include <cstddef>

// Problem constants
#define V_ 10000
#define E_ 512
#define H_ 1024
#define L_ 2
#define B_ 64
#define T_ 128
#define G4_ (4 * H_)                 // 4096 gate width
#define SLOT (3 * 128 * 64 * 8)      // shorts per u_ps timestep slot (3 planes)
#define PSTR 65536                   // shorts per u_ps plane (128*64*8)

typedef __attribute__((ext_vector_type(8))) short bf16x8;
typedef __attribute__((ext_vector_type(4))) float f32x4;

// ---------------------------------------------------------------------------
// bf16 split helpers (RNE; finite values only)
// a = b2f(h) + b2f(l) + b2f(q) + O(2^-27 |a|)
// ---------------------------------------------------------------------------
__device__ __forceinline__ unsigned short f2b(float x) {
    unsigned u = __float_as_uint(x);
    unsigned r = (u + 0x7FFFu + ((u >> 16) & 1u)) >> 16;
    return (unsigned short)r;
}
__device__ __forceinline__ float b2f(unsigned short h) {
    return __uint_as_float(((unsigned)h) << 16);
}
__device__ __forceinline__ void split3(float a, unsigned short& h, unsigned short& l, unsigned short& q) {
    h = f2b(a); float r = a - b2f(h);
    l = f2b(r); float r2 = r - b2f(l);
    q = f2b(r2);
}

// ---------------------------------------------------------------------------
// Embedding + concat: seq (T, B, E) rows m = t*64 + b
// ---------------------------------------------------------------------------
__global__ __launch_bounds__(128) void embed_kernel(
    const float* __restrict__ images, const int* __restrict__ captions,
    const float* __restrict__ table, float* __restrict__ seq)
{
    const int m = blockIdx.x;            // 0..8191
    const int t = m >> 6, b = m & 63;
    const float* src;
    if (t == 0) src = images + (size_t)b * E_;
    else        src = table + (size_t)captions[b * T_ + (t - 1)] * E_;
    float4 v = ((const float4*)src)[threadIdx.x];
    ((float4*)(seq + (size_t)m * E_))[threadIdx.x] = v;
}

// ---------------------------------------------------------------------------
// f32 -> 3 bf16 plane split (plane stride = n elements)
// ---------------------------------------------------------------------------
__global__ __launch_bounds__(256) void split_planes(
    const float* __restrict__ in, unsigned short* __restrict__ pl, size_t n)
{
    size_t i = ((size_t)blockIdx.x * 256 + threadIdx.x) * 4;
    if (i >= n) return;
    float4 v = *(const float4*)&in[i];
    unsigned short h[4], l[4], q[4];
    split3(v.x, h[0], l[0], q[0]); split3(v.y, h[1], l[1], q[1]);
    split3(v.z, h[2], l[2], q[2]); split3(v.w, h[3], l[3], q[3]);
    ushort4 hv = {h[0], h[1], h[2], h[3]};
    ushort4 lv = {l[0], l[1], l[2], l[3]};
    ushort4 qv = {q[0], q[1], q[2], q[3]};
    *(ushort4*)&pl[i]         = hv;
    *(ushort4*)&pl[n + i]     = lv;
    *(ushort4*)&pl[2 * n + i] = qv;
}

// ---------------------------------------------------------------------------
// Split-bf16x6 MFMA GEMM, in-kernel split of both operands (R2-verified).
// Used only for Whhr = W_hh @ W_hr (K,N f32 B). C = A(M,K) @ B(K,N), f32 out.
// ---------------------------------------------------------------------------
template<bool BNK>
__global__ __launch_bounds__(256) void mfma_gemm(
    const float* __restrict__ A, const float* __restrict__ Bm, float* __restrict__ C,
    int M, int N, int K,
    const float* __restrict__ bias1, const float* __restrict__ bias2)
{
    __shared__ unsigned short As[3][128][40];
    __shared__ unsigned short Bs[3][128][40];
    const int bm = blockIdx.y * 128, bn = blockIdx.x * 128;
    const int tid = threadIdx.x;
    const int lane = tid & 63, wid = tid >> 6;
    const int wm = wid >> 1, wn = wid & 1;
    const int lr = lane & 15, lk = (lane >> 4) * 8;

    f32x4 acc[4][4] = {};

    for (int k0 = 0; k0 < K; k0 += 32) {
        #pragma unroll
        for (int p = 0; p < 4; ++p) {
            int flat = p * 256 + tid;
            int c4 = flat & 7, r = flat >> 3;
            float4 v = *(const float4*)&A[(size_t)(bm + r) * K + k0 + c4 * 4];
            unsigned short h[4], l[4], q[4];
            split3(v.x, h[0], l[0], q[0]); split3(v.y, h[1], l[1], q[1]);
            split3(v.z, h[2], l[2], q[2]); split3(v.w, h[3], l[3], q[3]);
            unsigned* dh = (unsigned*)&As[0][r][c4 * 4];
            dh[0] = h[0] | ((unsigned)h[1] << 16); dh[1] = h[2] | ((unsigned)h[3] << 16);
            unsigned* dl = (unsigned*)&As[1][r][c4 * 4];
            dl[0] = l[0] | ((unsigned)l[1] << 16); dl[1] = l[2] | ((unsigned)l[3] << 16);
            unsigned* dq = (unsigned*)&As[2][r][c4 * 4];
            dq[0] = q[0] | ((unsigned)q[1] << 16); dq[1] = q[2] | ((unsigned)q[3] << 16);
        }
        if (BNK) {
            #pragma unroll
            for (int p = 0; p < 4; ++p) {
                int flat = p * 256 + tid;
                int c4 = flat & 7, r = flat >> 3;
                float4 v = *(const float4*)&Bm[(size_t)(bn + r) * K + k0 + c4 * 4];
                unsigned short h[4], l[4], q[4];
                split3(v.x, h[0], l[0], q[0]); split3(v.y, h[1], l[1], q[1]);
                split3(v.z, h[2], l[2], q[2]); split3(v.w, h[3], l[3], q[3]);
                unsigned* dh = (unsigned*)&Bs[0][r][c4 * 4];
                dh[0] = h[0] | ((unsigned)h[1] << 16); dh[1] = h[2] | ((unsigned)h[3] << 16);
                unsigned* dl = (unsigned*)&Bs[1][r][c4 * 4];
                dl[0] = l[0] | ((unsigned)l[1] << 16); dl[1] = l[2] | ((unsigned)l[3] << 16);
                unsigned* dq = (unsigned*)&Bs[2][r][c4 * 4];
                dq[0] = q[0] | ((unsigned)q[1] << 16); dq[1] = q[2] | ((unsigned)q[3] << 16);
            }
        } else {
            #pragma unroll
            for (int p = 0; p < 4; ++p) {
                int flat = p * 256 + tid;
                int n4 = flat & 31, kr = flat >> 5;
                float4 v = *(const float4*)&Bm[(size_t)(k0 + kr) * N + bn + n4 * 4];
                float vv[4] = {v.x, v.y, v.z, v.w};
                #pragma unroll
                for (int j = 0; j < 4; ++j) {
                    unsigned short h, l, q; split3(vv[j], h, l, q);
                    Bs[0][n4 * 4 + j][kr] = h;
                    Bs[1][n4 * 4 + j][kr] = l;
                    Bs[2][n4 * 4 + j][kr] = q;
                }
            }
        }
        __syncthreads();

        bf16x8 af[3][4], bf[3][4];
        #pragma unroll
        for (int pl = 0; pl < 3; ++pl)
            #pragma unroll
            for (int m = 0; m < 4; ++m) {
                af[pl][m] = *(const bf16x8*)&As[pl][wm * 64 + m * 16 + lr][lk];
                bf[pl][m] = *(const bf16x8*)&Bs[pl][wn * 64 + m * 16 + lr][lk];
            }
        #pragma unroll
        for (int m = 0; m < 4; ++m)
            #pragma unroll
            for (int n = 0; n < 4; ++n) {
                acc[m][n] = __builtin_amdgcn_mfma_f32_16x16x32_bf16(af[0][m], bf[0][n], acc[m][n], 0, 0, 0);
                acc[m][n] = __builtin_amdgcn_mfma_f32_16x16x32_bf16(af[0][m], bf[1][n], acc[m][n], 0, 0, 0);
                acc[m][n] = __builtin_amdgcn_mfma_f32_16x16x32_bf16(af[1][m], bf[0][n], acc[m][n], 0, 0, 0);
                acc[m][n] = __builtin_amdgcn_mfma_f32_16x16x32_bf16(af[1][m], bf[1][n], acc[m][n], 0, 0, 0);
                acc[m][n] = __builtin_amdgcn_mfma_f32_16x16x32_bf16(af[0][m], bf[2][n], acc[m][n], 0, 0, 0);
                acc[m][n] = __builtin_amdgcn_mfma_f32_16x16x32_bf16(af[2][m], bf[0][n], acc[m][n], 0, 0, 0);
            }
        __syncthreads();
    }

    float bv[4];
    #pragma unroll
    for (int n = 0; n < 4; ++n) {
        int col = bn + wn * 64 + n * 16 + lr;
        float x = 0.f;
        if (bias1) x += bias1[col];
        if (bias2) x += bias2[col];
        bv[n] = x;
    }
    #pragma unroll
    for (int m = 0; m < 4; ++m) {
        int rbase = bm + wm * 64 + m * 16 + (lane >> 4) * 4;
        #pragma unroll
        for (int n = 0; n < 4; ++n) {
            int col = bn + wn * 64 + n * 16 + lr;
            #pragma unroll
            for (int r = 0; r < 4; ++r)
                C[(size_t)(rbase + r) * N + col] = acc[m][n][r] + bv[n];
        }
    }
}

// ---------------------------------------------------------------------------
// X GEMM: Xr[t][col][b] = (seq/H0)(8192,512) @ W_ih^T + b_ih + b_hh
// A f32 split in-kernel; B pre-split planes [3][4096][512].
// ---------------------------------------------------------------------------
__global__ __launch_bounds__(256) void xgemm_kernel(
    const float* __restrict__ A, const unsigned short* __restrict__ Bpl,
    const float* __restrict__ bias1, const float* __restrict__ bias2,
    float* __restrict__ Xr)
{
    __shared__ unsigned short As[3][128][40];
    __shared__ unsigned short Bs[3][128][40];
    const int bm = blockIdx.y * 128, bn = blockIdx.x * 128;
    const int tid = threadIdx.x;
    const int lane = tid & 63, wid = tid >> 6;
    const int wm = wid >> 1, wn = wid & 1;
    const int lr = lane & 15, lg = lane >> 4, lk = lg * 8;

    f32x4 acc[4][4] = {};

    for (int k0 = 0; k0 < E_; k0 += 32) {
        #pragma unroll
        for (int p = 0; p < 4; ++p) {
            int flat = p * 256 + tid;
            int c4 = flat & 7, r = flat >> 3;
            float4 v = *(const float4*)&A[(size_t)(bm + r) * E_ + k0 + c4 * 4];
            unsigned short h[4], l[4], q[4];
            split3(v.x, h[0], l[0], q[0]); split3(v.y, h[1], l[1], q[1]);
            split3(v.z, h[2], l[2], q[2]); split3(v.w, h[3], l[3], q[3]);
            unsigned* dh = (unsigned*)&As[0][r][c4 * 4];
            dh[0] = h[0] | ((unsigned)h[1] << 16); dh[1] = h[2] | ((unsigned)h[3] << 16);
            unsigned* dl = (unsigned*)&As[1][r][c4 * 4];
            dl[0] = l[0] | ((unsigned)l[1] << 16); dl[1] = l[2] | ((unsigned)l[3] << 16);
            unsigned* dq = (unsigned*)&As[2][r][c4 * 4];
            dq[0] = q[0] | ((unsigned)q[1] << 16); dq[1] = q[2] | ((unsigned)q[3] << 16);
        }
        #pragma unroll
        for (int p6 = 0; p6 < 6; ++p6) {
            int f = p6 * 256 + tid;          // 0..1535
            int pl = f >> 9, rem = f & 511;
            int r = rem >> 2, g4 = rem & 3;
            const unsigned short* src = Bpl + (size_t)pl * (G4_ * E_) + (size_t)(bn + r) * E_ + k0 + g4 * 8;
            *(uint4*)&Bs[pl][r][g4 * 8] = *(const uint4*)src;
        }
        __syncthreads();

        bf16x8 af[3][4], bf[3][4];
        #pragma unroll
        for (int pl = 0; pl < 3; ++pl)
            #pragma unroll
            for (int m = 0; m < 4; ++m) {
                af[pl][m] = *(const bf16x8*)&As[pl][wm * 64 + m * 16 + lr][lk];
                bf[pl][m] = *(const bf16x8*)&Bs[pl][wn * 64 + m * 16 + lr][lk];
            }
        #pragma unroll
        for (int m = 0; m < 4; ++m)
            #pragma unroll
            for (int n = 0; n < 4; ++n) {
                acc[m][n] = __builtin_amdgcn_mfma_f32_16x16x32_bf16(af[0][m], bf[0][n], acc[m][n], 0, 0, 0);
                acc[m][n] = __builtin_amdgcn_mfma_f32_16x16x32_bf16(af[0][m], bf[1][n], acc[m][n], 0, 0, 0);
                acc[m][n] = __builtin_amdgcn_mfma_f32_16x16x32_bf16(af[1][m], bf[0][n], acc[m][n], 0, 0, 0);
                acc[m][n] = __builtin_amdgcn_mfma_f32_16x16x32_bf16(af[1][m], bf[1][n], acc[m][n], 0, 0, 0);
                acc[m][n] = __builtin_amdgcn_mfma_f32_16x16x32_bf16(af[0][m], bf[2][n], acc[m][n], 0, 0, 0);
                acc[m][n] = __builtin_amdgcn_mfma_f32_16x16x32_bf16(af[2][m], bf[0][n], acc[m][n], 0, 0, 0);
            }
        __syncthreads();
    }

    // epilogue: X transposed-gate layout [t][col][b]
    #pragma unroll
    for (int n = 0; n < 4; ++n) {
        int col = bn + wn * 64 + n * 16 + lr;
        float bv = bias1[col] + bias2[col];
        #pragma unroll
        for (int m = 0; m < 4; ++m) {
            int rbase = bm + wm * 64 + m * 16 + lg * 4;
            #pragma unroll
            for (int r = 0; r < 4; ++r) {
                int row = rbase + r;
                Xr[((size_t)(row >> 6) * G4_ + col) * 64 + (row & 63)] = acc[m][n][r] + bv;
            }
        }
    }
}

// ---------------------------------------------------------------------------
// Persistent 128-step LSTM recurrence (cooperative; one launch per layer).
// Block j owns h-dims j*4..j*4+3 (16 gate rows, ordered n = hh*4 + g).
// LDS: hi/lo planes of the 16 Whhr rows (64 KB, XOR-swizzled). q from global.
// u passed between steps as 3 bf16 planes in u_ps[t][pl][k8][b][8].
// ---------------------------------------------------------------------------
__global__ __launch_bounds__(256) void persistent_lstm(
    const float* __restrict__ Xr,              // [128][4096][64]
    const unsigned short* __restrict__ Wpl,    // [3][4096*1024]
    unsigned short* __restrict__ u_ps)         // [129][SLOT]
{
    namespace cg = cooperative_groups;
    cg::grid_group gg = cg::this_grid();

    __shared__ unsigned short Wlds[2][16][1024];   // exactly 64 KB

    const int tid = threadIdx.x;
    const int j = blockIdx.x;                      // 0..255
    const int lane = tid & 63, bq = tid >> 6;
    const int lr = lane & 15, lg = lane >> 4;

    // stage hi/lo weight planes (swizzled granules)
    for (int it = 0; it < 16; ++it) {
        int f = it * 256 + tid;                    // 0..4095
        int p = f >> 11, rem = f & 2047;
        int n = rem >> 7, g16 = rem & 127;
        int gr = (n & 3) * 1024 + j * 4 + (n >> 2);
        const unsigned short* src = Wpl + (size_t)p * (G4_ * H_) + (size_t)gr * H_ + g16 * 8;
        *(uint4*)&Wlds[p][n][(g16 ^ (n & 7)) * 8] = *(const uint4*)src;
    }
    __syncthreads();

    const int b = bq * 16 + lr;
    const int hh = lg;
    const int hcol = j * 4 + hh;
    const int k8o = hcol >> 3, jj = hcol & 7;
    const int grq = (lr & 3) * 1024 + j * 4 + (lr >> 2);
    const unsigned short* wqrow = Wpl + (size_t)2 * (G4_ * H_) + (size_t)grq * H_;
    const int uoff = b * 8;
    const int swzb = lr & 7;

    float c = 0.f;

    for (int t = 0; t < T_; ++t) {
        const unsigned short* ut = u_ps + (size_t)t * SLOT;
        float xg[4];
        #pragma unroll
        for (int g = 0; g < 4; ++g)
            xg[g] = Xr[((size_t)t * G4_ + g * 1024 + hcol) * 64 + b];

        f32x4 aa = {0.f, 0.f, 0.f, 0.f}, ab = {0.f, 0.f, 0.f, 0.f};
        #pragma unroll 8
        for (int ks = 0; ks < 32; ++ks) {
            int g16 = ks * 4 + lg;
            int swz = (g16 ^ swzb) * 8;
            bf16x8 wh = *(const bf16x8*)&Wlds[0][lr][swz];
            bf16x8 wl = *(const bf16x8*)&Wlds[1][lr][swz];
            bf16x8 wq = *(const bf16x8*)&wqrow[g16 * 8];
            bf16x8 uh = *(const bf16x8*)&ut[(size_t)g16 * 512 + uoff];
            bf16x8 ul = *(const bf16x8*)&ut[PSTR + (size_t)g16 * 512 + uoff];
            bf16x8 uq = *(const bf16x8*)&ut[2 * PSTR + (size_t)g16 * 512 + uoff];
            aa = __builtin_amdgcn_mfma_f32_16x16x32_bf16(wh, uh, aa, 0, 0, 0);
            aa = __builtin_amdgcn_mfma_f32_16x16x32_bf16(wh, ul, aa, 0, 0, 0);
            aa = __builtin_amdgcn_mfma_f32_16x16x32_bf16(wl, uh, aa, 0, 0, 0);
            ab = __builtin_amdgcn_mfma_f32_16x16x32_bf16(wl, ul, ab, 0, 0, 0);
            ab = __builtin_amdgcn_mfma_f32_16x16x32_bf16(wh, uq, ab, 0, 0, 0);
            ab = __builtin_amdgcn_mfma_f32_16x16x32_bf16(wq, uh, ab, 0, 0, 0);
        }
        float gi = aa[0] + ab[0] + xg[0];
        float gf = aa[1] + ab[1] + xg[1];
        float gv = aa[2] + ab[2] + xg[2];
        float go = aa[3] + ab[3] + xg[3];
        float si = 1.f / (1.f + __expf(-gi));
        float sf = 1.f / (1.f + __expf(-gf));
        float so = 1.f / (1.f + __expf(-go));
        float tg = tanhf(gv);
        c = sf * c + si * tg;
        float ho = so * tanhf(c);

        unsigned short sh, sl, sq;
        split3(ho, sh, sl, sq);
        unsigned short* dst = u_ps + (size_t)(t + 1) * SLOT + (size_t)(k8o * 64 + b) * 8 + jj;
        dst[0]        = sh;
        dst[PSTR]     = sl;
        dst[2 * PSTR] = sq;

        gg.sync();
    }
}

// ---------------------------------------------------------------------------
// Projection GEMM: C(8192,512) = U(8192,1024) @ W_hr^T
// A read fragment-direct from u_ps planes (pre-split); B f32 split in-kernel.
// ---------------------------------------------------------------------------
__global__ __launch_bounds__(256) void proj_gemm(
    const unsigned short* __restrict__ u_ps,   // [129][SLOT]
    const float* __restrict__ Whr,             // (512,1024) f32 (N,K)
    float* __restrict__ C)                     // (8192,512)
{
    __shared__ unsigned short Bs[3][128][40];
    const int bn = blockIdx.x * 128;           // N=512: 4 blocks
    const int bm = blockIdx.y * 128;           // M: 64 blocks
    const int tid = threadIdx.x;
    const int lane = tid & 63, wid = tid >> 6;
    const int wm = wid >> 1, wn = wid & 1;
    const int lr = lane & 15, lg = lane >> 4, lk = lg * 8;

    f32x4 acc[4][4] = {};
    const int t = (bm >> 6) + wm;
    const unsigned short* ut = u_ps + (size_t)(t + 1) * SLOT;

    for (int k0 = 0; k0 < H_; k0 += 32) {
        #pragma unroll
        for (int p = 0; p < 4; ++p) {
            int flat = p * 256 + tid;
            int c4 = flat & 7, r = flat >> 3;
            float4 v = *(const float4*)&Whr[(size_t)(bn + r) * H_ + k0 + c4 * 4];
            unsigned short h[4], l[4], q[4];
            split3(v.x, h[0], l[0], q[0]); split3(v.y, h[1], l[1], q[1]);
            split3(v.z, h[2], l[2], q[2]); split3(v.w, h[3], l[3], q[3]);
            unsigned* dh = (unsigned*)&Bs[0][r][c4 * 4];
            dh[0] = h[0] | ((unsigned)h[1] << 16); dh[1] = h[2] | ((unsigned)h[3] << 16);
            unsigned* dl = (unsigned*)&Bs[1][r][c4 * 4];
            dl[0] = l[0] | ((unsigned)l[1] << 16); dl[1] = l[2] | ((unsigned)l[3] << 16);
            unsigned* dq = (unsigned*)&Bs[2][r][c4 * 4];
            dq[0] = q[0] | ((unsigned)q[1] << 16); dq[1] = q[2] | ((unsigned)q[3] << 16);
        }
        __syncthreads();

        int ks = k0 >> 5;
        bf16x8 af[3][4], bf[3][4];
        #pragma unroll
        for (int pl = 0; pl < 3; ++pl)
            #pragma unroll
            for (int m = 0; m < 4; ++m) {
                af[pl][m] = *(const bf16x8*)&ut[(size_t)pl * PSTR + (size_t)((ks * 4 + lg) * 64 + m * 16 + lr) * 8];
                bf[pl][m] = *(const bf16x8*)&Bs[pl][wn * 64 + m * 16 + lr][lk];
            }
        #pragma unroll
        for (int m = 0; m < 4; ++m)
            #pragma unroll
            for (int n = 0; n < 4; ++n) {
                acc[m][n] = __builtin_amdgcn_mfma_f32_16x16x32_bf16(af[0][m], bf[0][n], acc[m][n], 0, 0, 0);
                acc[m][n] = __builtin_amdgcn_mfma_f32_16x16x32_bf16(af[0][m], bf[1][n], acc[m][n], 0, 0, 0);
                acc[m][n] = __builtin_amdgcn_mfma_f32_16x16x32_bf16(af[1][m], bf[0][n], acc[m][n], 0, 0, 0);
                acc[m][n] = __builtin_amdgcn_mfma_f32_16x16x32_bf16(af[1][m], bf[1][n], acc[m][n], 0, 0, 0);
                acc[m][n] = __builtin_amdgcn_mfma_f32_16x16x32_bf16(af[0][m], bf[2][n], acc[m][n], 0, 0, 0);
                acc[m][n] = __builtin_amdgcn_mfma_f32_16x16x32_bf16(af[2][m], bf[0][n], acc[m][n], 0, 0, 0);
            }
        __syncthreads();
    }

    #pragma unroll
    for (int m = 0; m < 4; ++m) {
        int rbase = bm + wm * 64 + m * 16 + lg * 4;
        #pragma unroll
        for (int n = 0; n < 4; ++n) {
            int col = bn + wn * 64 + n * 16 + lr;
            #pragma unroll
            for (int r = 0; r < 4; ++r)
                C[(size_t)(rbase + r) * E_ + col] = acc[m][n][r];
        }
    }
}

// ---------------------------------------------------------------------------
// Row softmax over E=512; input rows m = t*64+b, output row (b, t).
// ---------------------------------------------------------------------------
__global__ __launch_bounds__(256) void softmax_kernel(
    const float* __restrict__ LOG, float* __restrict__ out)
{
    const int lane = threadIdx.x & 63;
    const int r = blockIdx.x * 4 + (threadIdx.x >> 6);
    const float* src = LOG + (size_t)r * E_;
    float v[8];
    *(float4*)&v[0] = ((const float4*)src)[lane * 2];
    *(float4*)&v[4] = ((const float4*)src)[lane * 2 + 1];

    float m = v[0];
    #pragma unroll
    for (int i = 1; i < 8; ++i) m = fmaxf(m, v[i]);
    #pragma unroll
    for (int off = 32; off > 0; off >>= 1) m = fmaxf(m, __shfl_xor(m, off, 64));

    float s = 0.f;
    #pragma unroll
    for (int i = 0; i < 8; ++i) { v[i] = expf(v[i] - m); s += v[i]; }
    #pragma unroll
    for (int off = 32; off > 0; off >>= 1) s += __shfl_xor(s, off, 64);
    const float inv = 1.f / s;

    const int t = r >> 6, b = r & 63;
    float* dst = out + ((size_t)b * T_ + t) * E_;
    #pragma unroll
    for (int i = 0; i < 8; ++i) v[i] *= inv;
    ((float4*)dst)[lane * 2]     = *(float4*)&v[0];
    ((float4*)dst)[lane * 2 + 1] = *(float4*)&v[4];
}

// ---------------------------------------------------------------------------
extern "C" void kernel_launch(void* const* d_in, const int* in_sizes, int n_in,
                              void* d_out, int out_size, void* d_ws, size_t ws_size,
                              hipStream_t stream)
{
    const float* images   = (const float*)d_in[0];
    const int*   captions = (const int*)  d_in[1];
    const float* table    = (const float*)d_in[2];
    const float* W_ih     = (const float*)d_in[3];
    const float* W_hh     = (const float*)d_in[4];
    const float* W_hr     = (const float*)d_in[5];
    const float* b_ih     = (const float*)d_in[6];
    const float* b_hh     = (const float*)d_in[7];
    float* out = (float*)d_out;

    // Workspace layout (bytes)
    char* base = (char*)d_ws;
    float*          Xr      = (float*)base;                               // 134,217,728
    unsigned short* u_ps    = (unsigned short*)(base + 134217728);        //  50,724,864
    unsigned short* WhhrPl  = (unsigned short*)(base + 184942592);        //  25,165,824
    float*          seq     = (float*)(base + 210108416);                 //  16,777,216
    // aliases (sequentially dead regions)
    float*          WhhrF32 = (float*)((char*)u_ps + 786432);             // 16.8MB inside u_ps
    unsigned short* WihPl   = (unsigned short*)((char*)u_ps + 786432);    // 12.6MB inside u_ps
    float*          logits  = Xr;
    float*          H0      = seq;

    embed_kernel<<<T_ * B_, 128, 0, stream>>>(images, captions, table, seq);

    for (int l = 0; l < L_; ++l) {
        const float* wih = W_ih + (size_t)l * G4_ * E_;
        const float* whh = W_hh + (size_t)l * G4_ * E_;
        const float* whr = W_hr + (size_t)l * E_ * H_;
        const float* bih = b_ih + (size_t)l * G4_;
        const float* bhh = b_hh + (size_t)l * G4_;

        // Whhr = W_hh (4096,512) @ W_hr (512,1024), f32 (scratch inside u_ps)
        mfma_gemm<false><<<dim3(H_ / 128, G4_ / 128), 256, 0, stream>>>(
            whh, whr, WhhrF32, G4_, H_, E_, nullptr, nullptr);
        // split Whhr into 3 bf16 planes
        split_planes<<<(G4_ * H_) / 1024, 256, 0, stream>>>(WhhrF32, WhhrPl, (size_t)G4_ * H_);
        // split W_ih into 3 bf16 planes (overwrites WhhrF32 scratch)
        split_planes<<<(G4_ * E_) / 1024, 256, 0, stream>>>(wih, WihPl, (size_t)G4_ * E_);

        // X = inp @ W_ih^T + b_ih + b_hh, stored [t][col][b]
        const float* inp = (l == 0) ? seq : H0;
        xgemm_kernel<<<dim3(G4_ / 128, (T_ * B_) / 128), 256, 0, stream>>>(
            inp, WihPl, bih, bhh, Xr);

        // u(0) = 0
        hipMemsetAsync(u_ps, 0, SLOT * sizeof(unsigned short), stream);

        // 128-step recurrence, one cooperative launch
        {
            const float* xr_a = Xr;
            const unsigned short* wpl_a = WhhrPl;
            unsigned short* ups_a = u_ps;
            void* args[] = { (void*)&xr_a, (void*)&wpl_a, (void*)&ups_a };
            hipLaunchCooperativeKernel((const void*)persistent_lstm,
                                       dim3(256), dim3(256), args, 0, stream);
        }

        // project all u -> H0 (layer 0) or logits (layer 1)
        float* pdst = (l == 0) ? H0 : logits;
        proj_gemm<<<dim3(E_ / 128, (T_ * B_) / 128), 256, 0, stream>>>(u_ps, whr, pdst);
    }

    softmax_kernel<<<(T_ * B_) / 4, 256, 0, stream>>>(logits, out);

    (void)in_sizes; (void)n_in; (void)out_size; (void)ws_size;
}

// Round 4
// 6404.959 us; speedup vs baseline: 1.7479x; 1.7479x over previous
//
#include <hip/hip_runtime.h>
#include <cstdint>
#include <cstddef>

// Problem constants
#define V_ 10000
#define E_ 512
#define H_ 1024
#define L_ 2
#define B_ 64
#define T_ 128
#define G4_ (4 * H_)                 // 4096 gate width
#define SLOT (3 * 128 * 64 * 8)      // shorts per u_ps timestep slot (3 planes)
#define PSTR 65536                   // shorts per u_ps plane (128*64*8)

typedef __attribute__((ext_vector_type(8))) short bf16x8;
typedef __attribute__((ext_vector_type(4))) float f32x4;

// ---------------------------------------------------------------------------
// bf16 split helpers (RNE; finite values only)
// ---------------------------------------------------------------------------
__device__ __forceinline__ unsigned short f2b(float x) {
    unsigned u = __float_as_uint(x);
    unsigned r = (u + 0x7FFFu + ((u >> 16) & 1u)) >> 16;
    return (unsigned short)r;
}
__device__ __forceinline__ float b2f(unsigned short h) {
    return __uint_as_float(((unsigned)h) << 16);
}
__device__ __forceinline__ void split3(float a, unsigned short& h, unsigned short& l, unsigned short& q) {
    h = f2b(a); float r = a - b2f(h);
    l = f2b(r); float r2 = r - b2f(l);
    q = f2b(r2);
}

// ---------------------------------------------------------------------------
// Embedding + concat: seq (T, B, E) rows m = t*64 + b
// ---------------------------------------------------------------------------
__global__ __launch_bounds__(128) void embed_kernel(
    const float* __restrict__ images, const int* __restrict__ captions,
    const float* __restrict__ table, float* __restrict__ seq)
{
    const int m = blockIdx.x;            // 0..8191
    const int t = m >> 6, b = m & 63;
    const float* src;
    if (t == 0) src = images + (size_t)b * E_;
    else        src = table + (size_t)captions[b * T_ + (t - 1)] * E_;
    float4 v = ((const float4*)src)[threadIdx.x];
    ((float4*)(seq + (size_t)m * E_))[threadIdx.x] = v;
}

// ---------------------------------------------------------------------------
// f32 -> 3 bf16 plane split (plane stride = n elements)
// ---------------------------------------------------------------------------
__global__ __launch_bounds__(256) void split_planes(
    const float* __restrict__ in, unsigned short* __restrict__ pl, size_t n)
{
    size_t i = ((size_t)blockIdx.x * 256 + threadIdx.x) * 4;
    if (i >= n) return;
    float4 v = *(const float4*)&in[i];
    unsigned short h[4], l[4], q[4];
    split3(v.x, h[0], l[0], q[0]); split3(v.y, h[1], l[1], q[1]);
    split3(v.z, h[2], l[2], q[2]); split3(v.w, h[3], l[3], q[3]);
    ushort4 hv = {h[0], h[1], h[2], h[3]};
    ushort4 lv = {l[0], l[1], l[2], l[3]};
    ushort4 qv = {q[0], q[1], q[2], q[3]};
    *(ushort4*)&pl[i]         = hv;
    *(ushort4*)&pl[n + i]     = lv;
    *(ushort4*)&pl[2 * n + i] = qv;
}

// ---------------------------------------------------------------------------
// Split-bf16x6 MFMA GEMM, in-kernel split of both operands.
// Used only for Whhr = W_hh @ W_hr (K,N f32 B). C = A(M,K) @ B(K,N), f32 out.
// ---------------------------------------------------------------------------
template<bool BNK>
__global__ __launch_bounds__(256) void mfma_gemm(
    const float* __restrict__ A, const float* __restrict__ Bm, float* __restrict__ C,
    int M, int N, int K,
    const float* __restrict__ bias1, const float* __restrict__ bias2)
{
    __shared__ unsigned short As[3][128][40];
    __shared__ unsigned short Bs[3][128][40];
    const int bm = blockIdx.y * 128, bn = blockIdx.x * 128;
    const int tid = threadIdx.x;
    const int lane = tid & 63, wid = tid >> 6;
    const int wm = wid >> 1, wn = wid & 1;
    const int lr = lane & 15, lk = (lane >> 4) * 8;

    f32x4 acc[4][4] = {};

    for (int k0 = 0; k0 < K; k0 += 32) {
        #pragma unroll
        for (int p = 0; p < 4; ++p) {
            int flat = p * 256 + tid;
            int c4 = flat & 7, r = flat >> 3;
            float4 v = *(const float4*)&A[(size_t)(bm + r) * K + k0 + c4 * 4];
            unsigned short h[4], l[4], q[4];
            split3(v.x, h[0], l[0], q[0]); split3(v.y, h[1], l[1], q[1]);
            split3(v.z, h[2], l[2], q[2]); split3(v.w, h[3], l[3], q[3]);
            unsigned* dh = (unsigned*)&As[0][r][c4 * 4];
            dh[0] = h[0] | ((unsigned)h[1] << 16); dh[1] = h[2] | ((unsigned)h[3] << 16);
            unsigned* dl = (unsigned*)&As[1][r][c4 * 4];
            dl[0] = l[0] | ((unsigned)l[1] << 16); dl[1] = l[2] | ((unsigned)l[3] << 16);
            unsigned* dq = (unsigned*)&As[2][r][c4 * 4];
            dq[0] = q[0] | ((unsigned)q[1] << 16); dq[1] = q[2] | ((unsigned)q[3] << 16);
        }
        if (BNK) {
            #pragma unroll
            for (int p = 0; p < 4; ++p) {
                int flat = p * 256 + tid;
                int c4 = flat & 7, r = flat >> 3;
                float4 v = *(const float4*)&Bm[(size_t)(bn + r) * K + k0 + c4 * 4];
                unsigned short h[4], l[4], q[4];
                split3(v.x, h[0], l[0], q[0]); split3(v.y, h[1], l[1], q[1]);
                split3(v.z, h[2], l[2], q[2]); split3(v.w, h[3], l[3], q[3]);
                unsigned* dh = (unsigned*)&Bs[0][r][c4 * 4];
                dh[0] = h[0] | ((unsigned)h[1] << 16); dh[1] = h[2] | ((unsigned)h[3] << 16);
                unsigned* dl = (unsigned*)&Bs[1][r][c4 * 4];
                dl[0] = l[0] | ((unsigned)l[1] << 16); dl[1] = l[2] | ((unsigned)l[3] << 16);
                unsigned* dq = (unsigned*)&Bs[2][r][c4 * 4];
                dq[0] = q[0] | ((unsigned)q[1] << 16); dq[1] = q[2] | ((unsigned)q[3] << 16);
            }
        } else {
            #pragma unroll
            for (int p = 0; p < 4; ++p) {
                int flat = p * 256 + tid;
                int n4 = flat & 31, kr = flat >> 5;
                float4 v = *(const float4*)&Bm[(size_t)(k0 + kr) * N + bn + n4 * 4];
                float vv[4] = {v.x, v.y, v.z, v.w};
                #pragma unroll
                for (int j = 0; j < 4; ++j) {
                    unsigned short h, l, q; split3(vv[j], h, l, q);
                    Bs[0][n4 * 4 + j][kr] = h;
                    Bs[1][n4 * 4 + j][kr] = l;
                    Bs[2][n4 * 4 + j][kr] = q;
                }
            }
        }
        __syncthreads();

        bf16x8 af[3][4], bf[3][4];
        #pragma unroll
        for (int pl = 0; pl < 3; ++pl)
            #pragma unroll
            for (int m = 0; m < 4; ++m) {
                af[pl][m] = *(const bf16x8*)&As[pl][wm * 64 + m * 16 + lr][lk];
                bf[pl][m] = *(const bf16x8*)&Bs[pl][wn * 64 + m * 16 + lr][lk];
            }
        #pragma unroll
        for (int m = 0; m < 4; ++m)
            #pragma unroll
            for (int n = 0; n < 4; ++n) {
                acc[m][n] = __builtin_amdgcn_mfma_f32_16x16x32_bf16(af[0][m], bf[0][n], acc[m][n], 0, 0, 0);
                acc[m][n] = __builtin_amdgcn_mfma_f32_16x16x32_bf16(af[0][m], bf[1][n], acc[m][n], 0, 0, 0);
                acc[m][n] = __builtin_amdgcn_mfma_f32_16x16x32_bf16(af[1][m], bf[0][n], acc[m][n], 0, 0, 0);
                acc[m][n] = __builtin_amdgcn_mfma_f32_16x16x32_bf16(af[1][m], bf[1][n], acc[m][n], 0, 0, 0);
                acc[m][n] = __builtin_amdgcn_mfma_f32_16x16x32_bf16(af[0][m], bf[2][n], acc[m][n], 0, 0, 0);
                acc[m][n] = __builtin_amdgcn_mfma_f32_16x16x32_bf16(af[2][m], bf[0][n], acc[m][n], 0, 0, 0);
            }
        __syncthreads();
    }

    float bv[4];
    #pragma unroll
    for (int n = 0; n < 4; ++n) {
        int col = bn + wn * 64 + n * 16 + lr;
        float x = 0.f;
        if (bias1) x += bias1[col];
        if (bias2) x += bias2[col];
        bv[n] = x;
    }
    #pragma unroll
    for (int m = 0; m < 4; ++m) {
        int rbase = bm + wm * 64 + m * 16 + (lane >> 4) * 4;
        #pragma unroll
        for (int n = 0; n < 4; ++n) {
            int col = bn + wn * 64 + n * 16 + lr;
            #pragma unroll
            for (int r = 0; r < 4; ++r)
                C[(size_t)(rbase + r) * N + col] = acc[m][n][r] + bv[n];
        }
    }
}

// ---------------------------------------------------------------------------
// X GEMM: Xr[t][col][b] = (seq/H0)(8192,512) @ W_ih^T + b_ih + b_hh
// ---------------------------------------------------------------------------
__global__ __launch_bounds__(256) void xgemm_kernel(
    const float* __restrict__ A, const unsigned short* __restrict__ Bpl,
    const float* __restrict__ bias1, const float* __restrict__ bias2,
    float* __restrict__ Xr)
{
    __shared__ unsigned short As[3][128][40];
    __shared__ unsigned short Bs[3][128][40];
    const int bm = blockIdx.y * 128, bn = blockIdx.x * 128;
    const int tid = threadIdx.x;
    const int lane = tid & 63, wid = tid >> 6;
    const int wm = wid >> 1, wn = wid & 1;
    const int lr = lane & 15, lg = lane >> 4, lk = lg * 8;

    f32x4 acc[4][4] = {};

    for (int k0 = 0; k0 < E_; k0 += 32) {
        #pragma unroll
        for (int p = 0; p < 4; ++p) {
            int flat = p * 256 + tid;
            int c4 = flat & 7, r = flat >> 3;
            float4 v = *(const float4*)&A[(size_t)(bm + r) * E_ + k0 + c4 * 4];
            unsigned short h[4], l[4], q[4];
            split3(v.x, h[0], l[0], q[0]); split3(v.y, h[1], l[1], q[1]);
            split3(v.z, h[2], l[2], q[2]); split3(v.w, h[3], l[3], q[3]);
            unsigned* dh = (unsigned*)&As[0][r][c4 * 4];
            dh[0] = h[0] | ((unsigned)h[1] << 16); dh[1] = h[2] | ((unsigned)h[3] << 16);
            unsigned* dl = (unsigned*)&As[1][r][c4 * 4];
            dl[0] = l[0] | ((unsigned)l[1] << 16); dl[1] = l[2] | ((unsigned)l[3] << 16);
            unsigned* dq = (unsigned*)&As[2][r][c4 * 4];
            dq[0] = q[0] | ((unsigned)q[1] << 16); dq[1] = q[2] | ((unsigned)q[3] << 16);
        }
        #pragma unroll
        for (int p6 = 0; p6 < 6; ++p6) {
            int f = p6 * 256 + tid;
            int pl = f >> 9, rem = f & 511;
            int r = rem >> 2, g4 = rem & 3;
            const unsigned short* src = Bpl + (size_t)pl * (G4_ * E_) + (size_t)(bn + r) * E_ + k0 + g4 * 8;
            *(uint4*)&Bs[pl][r][g4 * 8] = *(const uint4*)src;
        }
        __syncthreads();

        bf16x8 af[3][4], bf[3][4];
        #pragma unroll
        for (int pl = 0; pl < 3; ++pl)
            #pragma unroll
            for (int m = 0; m < 4; ++m) {
                af[pl][m] = *(const bf16x8*)&As[pl][wm * 64 + m * 16 + lr][lk];
                bf[pl][m] = *(const bf16x8*)&Bs[pl][wn * 64 + m * 16 + lr][lk];
            }
        #pragma unroll
        for (int m = 0; m < 4; ++m)
            #pragma unroll
            for (int n = 0; n < 4; ++n) {
                acc[m][n] = __builtin_amdgcn_mfma_f32_16x16x32_bf16(af[0][m], bf[0][n], acc[m][n], 0, 0, 0);
                acc[m][n] = __builtin_amdgcn_mfma_f32_16x16x32_bf16(af[0][m], bf[1][n], acc[m][n], 0, 0, 0);
                acc[m][n] = __builtin_amdgcn_mfma_f32_16x16x32_bf16(af[1][m], bf[0][n], acc[m][n], 0, 0, 0);
                acc[m][n] = __builtin_amdgcn_mfma_f32_16x16x32_bf16(af[1][m], bf[1][n], acc[m][n], 0, 0, 0);
                acc[m][n] = __builtin_amdgcn_mfma_f32_16x16x32_bf16(af[0][m], bf[2][n], acc[m][n], 0, 0, 0);
                acc[m][n] = __builtin_amdgcn_mfma_f32_16x16x32_bf16(af[2][m], bf[0][n], acc[m][n], 0, 0, 0);
            }
        __syncthreads();
    }

    #pragma unroll
    for (int n = 0; n < 4; ++n) {
        int col = bn + wn * 64 + n * 16 + lr;
        float bv = bias1[col] + bias2[col];
        #pragma unroll
        for (int m = 0; m < 4; ++m) {
            int rbase = bm + wm * 64 + m * 16 + lg * 4;
            #pragma unroll
            for (int r = 0; r < 4; ++r) {
                int row = rbase + r;
                Xr[((size_t)(row >> 6) * G4_ + col) * 64 + (row & 63)] = acc[m][n][r] + bv;
            }
        }
    }
}

// ---------------------------------------------------------------------------
// Persistent 128-step LSTM recurrence. cg::sync replaced by a lean two-level
// agent-scope barrier: 32 cacheline-spaced counters (8 blocks each),
// monotone targets (no reset), wave0 spins, ACQUIRE pulls buffer_inv.
// ---------------------------------------------------------------------------
__global__ __launch_bounds__(256) void persistent_lstm(
    const float* __restrict__ Xr,              // [128][4096][64]
    const unsigned short* __restrict__ Wpl,    // [3][4096*1024]
    unsigned short* __restrict__ u_ps,         // [129][SLOT]
    unsigned int* bar)                         // 32 counters, 64B apart
{
    __shared__ unsigned short Wlds[2][16][1024];   // exactly 64 KB

    const int tid = threadIdx.x;
    const int j = blockIdx.x;                      // 0..255
    const int lane = tid & 63, bq = tid >> 6;
    const int lr = lane & 15, lg = lane >> 4;

    // stage hi/lo weight planes (swizzled granules)
    for (int it = 0; it < 16; ++it) {
        int f = it * 256 + tid;                    // 0..4095
        int p = f >> 11, rem = f & 2047;
        int n = rem >> 7, g16 = rem & 127;
        int gr = (n & 3) * 1024 + j * 4 + (n >> 2);
        const unsigned short* src = Wpl + (size_t)p * (G4_ * H_) + (size_t)gr * H_ + g16 * 8;
        *(uint4*)&Wlds[p][n][(g16 ^ (n & 7)) * 8] = *(const uint4*)src;
    }
    __syncthreads();

    const int b = bq * 16 + lr;
    const int hh = lg;
    const int hcol = j * 4 + hh;
    const int k8o = hcol >> 3, jj = hcol & 7;
    const int grq = (lr & 3) * 1024 + j * 4 + (lr >> 2);
    const unsigned short* wqrow = Wpl + (size_t)2 * (G4_ * H_) + (size_t)grq * H_;
    const int uoff = b * 8;
    const int swzb = lr & 7;

    float c = 0.f;

    for (int t = 0; t < T_; ++t) {
        const unsigned short* ut = u_ps + (size_t)t * SLOT;
        float xg[4];
        #pragma unroll
        for (int g = 0; g < 4; ++g)
            xg[g] = Xr[((size_t)t * G4_ + g * 1024 + hcol) * 64 + b];

        f32x4 aa = {0.f, 0.f, 0.f, 0.f}, ab = {0.f, 0.f, 0.f, 0.f};
        #pragma unroll 8
        for (int ks = 0; ks < 32; ++ks) {
            int g16 = ks * 4 + lg;
            int swz = (g16 ^ swzb) * 8;
            bf16x8 wh = *(const bf16x8*)&Wlds[0][lr][swz];
            bf16x8 wl = *(const bf16x8*)&Wlds[1][lr][swz];
            bf16x8 wq = *(const bf16x8*)&wqrow[g16 * 8];
            bf16x8 uh = *(const bf16x8*)&ut[(size_t)g16 * 512 + uoff];
            bf16x8 ul = *(const bf16x8*)&ut[PSTR + (size_t)g16 * 512 + uoff];
            bf16x8 uq = *(const bf16x8*)&ut[2 * PSTR + (size_t)g16 * 512 + uoff];
            aa = __builtin_amdgcn_mfma_f32_16x16x32_bf16(wh, uh, aa, 0, 0, 0);
            aa = __builtin_amdgcn_mfma_f32_16x16x32_bf16(wh, ul, aa, 0, 0, 0);
            aa = __builtin_amdgcn_mfma_f32_16x16x32_bf16(wl, uh, aa, 0, 0, 0);
            ab = __builtin_amdgcn_mfma_f32_16x16x32_bf16(wl, ul, ab, 0, 0, 0);
            ab = __builtin_amdgcn_mfma_f32_16x16x32_bf16(wh, uq, ab, 0, 0, 0);
            ab = __builtin_amdgcn_mfma_f32_16x16x32_bf16(wq, uh, ab, 0, 0, 0);
        }
        float gi = aa[0] + ab[0] + xg[0];
        float gf = aa[1] + ab[1] + xg[1];
        float gv = aa[2] + ab[2] + xg[2];
        float go = aa[3] + ab[3] + xg[3];
        float si = 1.f / (1.f + __expf(-gi));
        float sf = 1.f / (1.f + __expf(-gf));
        float so = 1.f / (1.f + __expf(-go));
        float tg = tanhf(gv);
        c = sf * c + si * tg;
        float ho = so * tanhf(c);

        unsigned short sh, sl, sq;
        split3(ho, sh, sl, sq);
        unsigned short* dst = u_ps + (size_t)(t + 1) * SLOT + (size_t)(k8o * 64 + b) * 8 + jj;
        dst[0]        = sh;
        dst[PSTR]     = sl;
        dst[2 * PSTR] = sq;

        if (t != T_ - 1) {
            // ---- lean grid barrier ----
            __syncthreads();   // drains this block's u stores (vmcnt 0) to L2
            if (tid == 0)
                __hip_atomic_fetch_add(&bar[(j & 31) * 16], 1u,
                                       __ATOMIC_RELEASE, __HIP_MEMORY_SCOPE_AGENT);
            if (tid < 32) {
                const unsigned tgt = (unsigned)(t + 1) * 8u;
                while (__hip_atomic_load(&bar[tid * 16],
                                         __ATOMIC_RELAXED, __HIP_MEMORY_SCOPE_AGENT) < tgt) {}
                (void)__hip_atomic_load(&bar[tid * 16],
                                        __ATOMIC_ACQUIRE, __HIP_MEMORY_SCOPE_AGENT);
            }
            __syncthreads();
        }
    }
}

// ---------------------------------------------------------------------------
// Projection GEMM: C(8192,512) = U(8192,1024) @ W_hr^T
// ---------------------------------------------------------------------------
__global__ __launch_bounds__(256) void proj_gemm(
    const unsigned short* __restrict__ u_ps,   // [129][SLOT]
    const float* __restrict__ Whr,             // (512,1024) f32 (N,K)
    float* __restrict__ C)                     // (8192,512)
{
    __shared__ unsigned short Bs[3][128][40];
    const int bn = blockIdx.x * 128;
    const int bm = blockIdx.y * 128;
    const int tid = threadIdx.x;
    const int lane = tid & 63, wid = tid >> 6;
    const int wm = wid >> 1, wn = wid & 1;
    const int lr = lane & 15, lg = lane >> 4, lk = lg * 8;

    f32x4 acc[4][4] = {};
    const int t = (bm >> 6) + wm;
    const unsigned short* ut = u_ps + (size_t)(t + 1) * SLOT;

    for (int k0 = 0; k0 < H_; k0 += 32) {
        #pragma unroll
        for (int p = 0; p < 4; ++p) {
            int flat = p * 256 + tid;
            int c4 = flat & 7, r = flat >> 3;
            float4 v = *(const float4*)&Whr[(size_t)(bn + r) * H_ + k0 + c4 * 4];
            unsigned short h[4], l[4], q[4];
            split3(v.x, h[0], l[0], q[0]); split3(v.y, h[1], l[1], q[1]);
            split3(v.z, h[2], l[2], q[2]); split3(v.w, h[3], l[3], q[3]);
            unsigned* dh = (unsigned*)&Bs[0][r][c4 * 4];
            dh[0] = h[0] | ((unsigned)h[1] << 16); dh[1] = h[2] | ((unsigned)h[3] << 16);
            unsigned* dl = (unsigned*)&Bs[1][r][c4 * 4];
            dl[0] = l[0] | ((unsigned)l[1] << 16); dl[1] = l[2] | ((unsigned)l[3] << 16);
            unsigned* dq = (unsigned*)&Bs[2][r][c4 * 4];
            dq[0] = q[0] | ((unsigned)q[1] << 16); dq[1] = q[2] | ((unsigned)q[3] << 16);
        }
        __syncthreads();

        int ks = k0 >> 5;
        bf16x8 af[3][4], bf[3][4];
        #pragma unroll
        for (int pl = 0; pl < 3; ++pl)
            #pragma unroll
            for (int m = 0; m < 4; ++m) {
                af[pl][m] = *(const bf16x8*)&ut[(size_t)pl * PSTR + (size_t)((ks * 4 + lg) * 64 + m * 16 + lr) * 8];
                bf[pl][m] = *(const bf16x8*)&Bs[pl][wn * 64 + m * 16 + lr][lk];
            }
        #pragma unroll
        for (int m = 0; m < 4; ++m)
            #pragma unroll
            for (int n = 0; n < 4; ++n) {
                acc[m][n] = __builtin_amdgcn_mfma_f32_16x16x32_bf16(af[0][m], bf[0][n], acc[m][n], 0, 0, 0);
                acc[m][n] = __builtin_amdgcn_mfma_f32_16x16x32_bf16(af[0][m], bf[1][n], acc[m][n], 0, 0, 0);
                acc[m][n] = __builtin_amdgcn_mfma_f32_16x16x32_bf16(af[1][m], bf[0][n], acc[m][n], 0, 0, 0);
                acc[m][n] = __builtin_amdgcn_mfma_f32_16x16x32_bf16(af[1][m], bf[1][n], acc[m][n], 0, 0, 0);
                acc[m][n] = __builtin_amdgcn_mfma_f32_16x16x32_bf16(af[0][m], bf[2][n], acc[m][n], 0, 0, 0);
                acc[m][n] = __builtin_amdgcn_mfma_f32_16x16x32_bf16(af[2][m], bf[0][n], acc[m][n], 0, 0, 0);
            }
        __syncthreads();
    }

    #pragma unroll
    for (int m = 0; m < 4; ++m) {
        int rbase = bm + wm * 64 + m * 16 + lg * 4;
        #pragma unroll
        for (int n = 0; n < 4; ++n) {
            int col = bn + wn * 64 + n * 16 + lr;
            #pragma unroll
            for (int r = 0; r < 4; ++r)
                C[(size_t)(rbase + r) * E_ + col] = acc[m][n][r];
        }
    }
}

// ---------------------------------------------------------------------------
// Row softmax over E=512; input rows m = t*64+b, output row (b, t).
// ---------------------------------------------------------------------------
__global__ __launch_bounds__(256) void softmax_kernel(
    const float* __restrict__ LOG, float* __restrict__ out)
{
    const int lane = threadIdx.x & 63;
    const int r = blockIdx.x * 4 + (threadIdx.x >> 6);
    const float* src = LOG + (size_t)r * E_;
    float v[8];
    *(float4*)&v[0] = ((const float4*)src)[lane * 2];
    *(float4*)&v[4] = ((const float4*)src)[lane * 2 + 1];

    float m = v[0];
    #pragma unroll
    for (int i = 1; i < 8; ++i) m = fmaxf(m, v[i]);
    #pragma unroll
    for (int off = 32; off > 0; off >>= 1) m = fmaxf(m, __shfl_xor(m, off, 64));

    float s = 0.f;
    #pragma unroll
    for (int i = 0; i < 8; ++i) { v[i] = expf(v[i] - m); s += v[i]; }
    #pragma unroll
    for (int off = 32; off > 0; off >>= 1) s += __shfl_xor(s, off, 64);
    const float inv = 1.f / s;

    const int t = r >> 6, b = r & 63;
    float* dst = out + ((size_t)b * T_ + t) * E_;
    #pragma unroll
    for (int i = 0; i < 8; ++i) v[i] *= inv;
    ((float4*)dst)[lane * 2]     = *(float4*)&v[0];
    ((float4*)dst)[lane * 2 + 1] = *(float4*)&v[4];
}

// ---------------------------------------------------------------------------
extern "C" void kernel_launch(void* const* d_in, const int* in_sizes, int n_in,
                              void* d_out, int out_size, void* d_ws, size_t ws_size,
                              hipStream_t stream)
{
    const float* images   = (const float*)d_in[0];
    const int*   captions = (const int*)  d_in[1];
    const float* table    = (const float*)d_in[2];
    const float* W_ih     = (const float*)d_in[3];
    const float* W_hh     = (const float*)d_in[4];
    const float* W_hr     = (const float*)d_in[5];
    const float* b_ih     = (const float*)d_in[6];
    const float* b_hh     = (const float*)d_in[7];
    float* out = (float*)d_out;

    // Workspace layout (bytes)
    char* base = (char*)d_ws;
    float*          Xr      = (float*)base;                               // 134,217,728
    unsigned int*   bar     = (unsigned int*)(base + 134217728);          //       4,096
    unsigned short* u_ps    = (unsigned short*)(base + 134221824);        //  50,724,864
    unsigned short* WhhrPl  = (unsigned short*)(base + 184946688);        //  25,165,824
    float*          seq     = (float*)(base + 210112512);                 //  16,777,216
    // aliases (sequentially dead regions)
    float*          WhhrF32 = (float*)((char*)u_ps + 786432);
    unsigned short* WihPl   = (unsigned short*)((char*)u_ps + 786432);
    float*          logits  = Xr;
    float*          H0      = seq;

    embed_kernel<<<T_ * B_, 128, 0, stream>>>(images, captions, table, seq);

    for (int l = 0; l < L_; ++l) {
        const float* wih = W_ih + (size_t)l * G4_ * E_;
        const float* whh = W_hh + (size_t)l * G4_ * E_;
        const float* whr = W_hr + (size_t)l * E_ * H_;
        const float* bih = b_ih + (size_t)l * G4_;
        const float* bhh = b_hh + (size_t)l * G4_;

        // Whhr = W_hh (4096,512) @ W_hr (512,1024), f32 (scratch inside u_ps)
        mfma_gemm<false><<<dim3(H_ / 128, G4_ / 128), 256, 0, stream>>>(
            whh, whr, WhhrF32, G4_, H_, E_, nullptr, nullptr);
        split_planes<<<(G4_ * H_) / 1024, 256, 0, stream>>>(WhhrF32, WhhrPl, (size_t)G4_ * H_);
        split_planes<<<(G4_ * E_) / 1024, 256, 0, stream>>>(wih, WihPl, (size_t)G4_ * E_);

        // X = inp @ W_ih^T + b_ih + b_hh, stored [t][col][b]
        const float* inp = (l == 0) ? seq : H0;
        xgemm_kernel<<<dim3(G4_ / 128, (T_ * B_) / 128), 256, 0, stream>>>(
            inp, WihPl, bih, bhh, Xr);

        // zero u(0) and barrier state
        hipMemsetAsync(u_ps, 0, SLOT * sizeof(unsigned short), stream);
        hipMemsetAsync(bar, 0, 4096, stream);

        // 128-step recurrence, one cooperative launch (residency guarantee)
        {
            const float* xr_a = Xr;
            const unsigned short* wpl_a = WhhrPl;
            unsigned short* ups_a = u_ps;
            unsigned int* bar_a = bar;
            void* args[] = { (void*)&xr_a, (void*)&wpl_a, (void*)&ups_a, (void*)&bar_a };
            hipLaunchCooperativeKernel((const void*)persistent_lstm,
                                       dim3(256), dim3(256), args, 0, stream);
        }

        // project all u -> H0 (layer 0) or logits (layer 1)
        float* pdst = (l == 0) ? H0 : logits;
        proj_gemm<<<dim3(E_ / 128, (T_ * B_) / 128), 256, 0, stream>>>(u_ps, whr, pdst);
    }

    softmax_kernel<<<(T_ * B_) / 4, 256, 0, stream>>>(logits, out);

    (void)in_sizes; (void)n_in; (void)out_size; (void)ws_size;
}

// Round 6
// 5330.818 us; speedup vs baseline: 2.1001x; 1.2015x over previous
//
#include <hip/hip_runtime.h>
#include <cstdint>
#include <cstddef>

// Problem constants
#define V_ 10000
#define E_ 512
#define H_ 1024
#define L_ 2
#define B_ 64
#define T_ 128
#define G4_ (4 * H_)                 // 4096 gate width
#define SLOT (3 * 128 * 64 * 8)      // shorts per u_ps timestep slot (3 planes)
#define PSTR 65536                   // shorts per u_ps plane (128*64*8)

typedef __attribute__((ext_vector_type(8))) short bf16x8;
typedef __attribute__((ext_vector_type(4))) float f32x4;
typedef __attribute__((ext_vector_type(4))) unsigned int u32x4;

// ---------------------------------------------------------------------------
// bf16 split helpers (RNE; finite values only)
// ---------------------------------------------------------------------------
__device__ __forceinline__ unsigned short f2b(float x) {
    unsigned u = __float_as_uint(x);
    unsigned r = (u + 0x7FFFu + ((u >> 16) & 1u)) >> 16;
    return (unsigned short)r;
}
__device__ __forceinline__ float b2f(unsigned short h) {
    return __uint_as_float(((unsigned)h) << 16);
}
__device__ __forceinline__ void split3(float a, unsigned short& h, unsigned short& l, unsigned short& q) {
    h = f2b(a); float r = a - b2f(h);
    l = f2b(r); float r2 = r - b2f(l);
    q = f2b(r2);
}

// ---------------------------------------------------------------------------
// Embedding + concat: seq (T, B, E) rows m = t*64 + b
// ---------------------------------------------------------------------------
__global__ __launch_bounds__(128) void embed_kernel(
    const float* __restrict__ images, const int* __restrict__ captions,
    const float* __restrict__ table, float* __restrict__ seq)
{
    const int m = blockIdx.x;            // 0..8191
    const int t = m >> 6, b = m & 63;
    const float* src;
    if (t == 0) src = images + (size_t)b * E_;
    else        src = table + (size_t)captions[b * T_ + (t - 1)] * E_;
    float4 v = ((const float4*)src)[threadIdx.x];
    ((float4*)(seq + (size_t)m * E_))[threadIdx.x] = v;
}

// ---------------------------------------------------------------------------
// f32 -> 3 bf16 plane split (plane stride = n elements)
// ---------------------------------------------------------------------------
__global__ __launch_bounds__(256) void split_planes(
    const float* __restrict__ in, unsigned short* __restrict__ pl, size_t n)
{
    size_t i = ((size_t)blockIdx.x * 256 + threadIdx.x) * 4;
    if (i >= n) return;
    float4 v = *(const float4*)&in[i];
    unsigned short h[4], l[4], q[4];
    split3(v.x, h[0], l[0], q[0]); split3(v.y, h[1], l[1], q[1]);
    split3(v.z, h[2], l[2], q[2]); split3(v.w, h[3], l[3], q[3]);
    ushort4 hv = {h[0], h[1], h[2], h[3]};
    ushort4 lv = {l[0], l[1], l[2], l[3]};
    ushort4 qv = {q[0], q[1], q[2], q[3]};
    *(ushort4*)&pl[i]         = hv;
    *(ushort4*)&pl[n + i]     = lv;
    *(ushort4*)&pl[2 * n + i] = qv;
}

// ---------------------------------------------------------------------------
// Split-bf16x6 MFMA GEMM, in-kernel split of both operands.
// Used only for Whhr = W_hh @ W_hr (K,N f32 B). C = A(M,K) @ B(K,N), f32 out.
// ---------------------------------------------------------------------------
template<bool BNK>
__global__ __launch_bounds__(256) void mfma_gemm(
    const float* __restrict__ A, const float* __restrict__ Bm, float* __restrict__ C,
    int M, int N, int K,
    const float* __restrict__ bias1, const float* __restrict__ bias2)
{
    __shared__ unsigned short As[3][128][40];
    __shared__ unsigned short Bs[3][128][40];
    const int bm = blockIdx.y * 128, bn = blockIdx.x * 128;
    const int tid = threadIdx.x;
    const int lane = tid & 63, wid = tid >> 6;
    const int wm = wid >> 1, wn = wid & 1;
    const int lr = lane & 15, lk = (lane >> 4) * 8;

    f32x4 acc[4][4] = {};

    for (int k0 = 0; k0 < K; k0 += 32) {
        #pragma unroll
        for (int p = 0; p < 4; ++p) {
            int flat = p * 256 + tid;
            int c4 = flat & 7, r = flat >> 3;
            float4 v = *(const float4*)&A[(size_t)(bm + r) * K + k0 + c4 * 4];
            unsigned short h[4], l[4], q[4];
            split3(v.x, h[0], l[0], q[0]); split3(v.y, h[1], l[1], q[1]);
            split3(v.z, h[2], l[2], q[2]); split3(v.w, h[3], l[3], q[3]);
            unsigned* dh = (unsigned*)&As[0][r][c4 * 4];
            dh[0] = h[0] | ((unsigned)h[1] << 16); dh[1] = h[2] | ((unsigned)h[3] << 16);
            unsigned* dl = (unsigned*)&As[1][r][c4 * 4];
            dl[0] = l[0] | ((unsigned)l[1] << 16); dl[1] = l[2] | ((unsigned)l[3] << 16);
            unsigned* dq = (unsigned*)&As[2][r][c4 * 4];
            dq[0] = q[0] | ((unsigned)q[1] << 16); dq[1] = q[2] | ((unsigned)q[3] << 16);
        }
        if (BNK) {
            #pragma unroll
            for (int p = 0; p < 4; ++p) {
                int flat = p * 256 + tid;
                int c4 = flat & 7, r = flat >> 3;
                float4 v = *(const float4*)&Bm[(size_t)(bn + r) * K + k0 + c4 * 4];
                unsigned short h[4], l[4], q[4];
                split3(v.x, h[0], l[0], q[0]); split3(v.y, h[1], l[1], q[1]);
                split3(v.z, h[2], l[2], q[2]); split3(v.w, h[3], l[3], q[3]);
                unsigned* dh = (unsigned*)&Bs[0][r][c4 * 4];
                dh[0] = h[0] | ((unsigned)h[1] << 16); dh[1] = h[2] | ((unsigned)h[3] << 16);
                unsigned* dl = (unsigned*)&Bs[1][r][c4 * 4];
                dl[0] = l[0] | ((unsigned)l[1] << 16); dl[1] = l[2] | ((unsigned)l[3] << 16);
                unsigned* dq = (unsigned*)&Bs[2][r][c4 * 4];
                dq[0] = q[0] | ((unsigned)q[1] << 16); dq[1] = q[2] | ((unsigned)q[3] << 16);
            }
        } else {
            #pragma unroll
            for (int p = 0; p < 4; ++p) {
                int flat = p * 256 + tid;
                int n4 = flat & 31, kr = flat >> 5;
                float4 v = *(const float4*)&Bm[(size_t)(k0 + kr) * N + bn + n4 * 4];
                float vv[4] = {v.x, v.y, v.z, v.w};
                #pragma unroll
                for (int jj = 0; jj < 4; ++jj) {
                    unsigned short h, l, q; split3(vv[jj], h, l, q);
                    Bs[0][n4 * 4 + jj][kr] = h;
                    Bs[1][n4 * 4 + jj][kr] = l;
                    Bs[2][n4 * 4 + jj][kr] = q;
                }
            }
        }
        __syncthreads();

        bf16x8 af[3][4], bf[3][4];
        #pragma unroll
        for (int pl = 0; pl < 3; ++pl)
            #pragma unroll
            for (int m = 0; m < 4; ++m) {
                af[pl][m] = *(const bf16x8*)&As[pl][wm * 64 + m * 16 + lr][lk];
                bf[pl][m] = *(const bf16x8*)&Bs[pl][wn * 64 + m * 16 + lr][lk];
            }
        #pragma unroll
        for (int m = 0; m < 4; ++m)
            #pragma unroll
            for (int n = 0; n < 4; ++n) {
                acc[m][n] = __builtin_amdgcn_mfma_f32_16x16x32_bf16(af[0][m], bf[0][n], acc[m][n], 0, 0, 0);
                acc[m][n] = __builtin_amdgcn_mfma_f32_16x16x32_bf16(af[0][m], bf[1][n], acc[m][n], 0, 0, 0);
                acc[m][n] = __builtin_amdgcn_mfma_f32_16x16x32_bf16(af[1][m], bf[0][n], acc[m][n], 0, 0, 0);
                acc[m][n] = __builtin_amdgcn_mfma_f32_16x16x32_bf16(af[1][m], bf[1][n], acc[m][n], 0, 0, 0);
                acc[m][n] = __builtin_amdgcn_mfma_f32_16x16x32_bf16(af[0][m], bf[2][n], acc[m][n], 0, 0, 0);
                acc[m][n] = __builtin_amdgcn_mfma_f32_16x16x32_bf16(af[2][m], bf[0][n], acc[m][n], 0, 0, 0);
            }
        __syncthreads();
    }

    float bv[4];
    #pragma unroll
    for (int n = 0; n < 4; ++n) {
        int col = bn + wn * 64 + n * 16 + lr;
        float x = 0.f;
        if (bias1) x += bias1[col];
        if (bias2) x += bias2[col];
        bv[n] = x;
    }
    #pragma unroll
    for (int m = 0; m < 4; ++m) {
        int rbase = bm + wm * 64 + m * 16 + (lane >> 4) * 4;
        #pragma unroll
        for (int n = 0; n < 4; ++n) {
            int col = bn + wn * 64 + n * 16 + lr;
            #pragma unroll
            for (int r = 0; r < 4; ++r)
                C[(size_t)(rbase + r) * N + col] = acc[m][n][r] + bv[n];
        }
    }
}

// ---------------------------------------------------------------------------
// X GEMM: Xr[t][col][b] = (seq/H0)(8192,512) @ W_ih^T + b_ih + b_hh
// ---------------------------------------------------------------------------
__global__ __launch_bounds__(256) void xgemm_kernel(
    const float* __restrict__ A, const unsigned short* __restrict__ Bpl,
    const float* __restrict__ bias1, const float* __restrict__ bias2,
    float* __restrict__ Xr)
{
    __shared__ unsigned short As[3][128][40];
    __shared__ unsigned short Bs[3][128][40];
    const int bm = blockIdx.y * 128, bn = blockIdx.x * 128;
    const int tid = threadIdx.x;
    const int lane = tid & 63, wid = tid >> 6;
    const int wm = wid >> 1, wn = wid & 1;
    const int lr = lane & 15, lg = lane >> 4, lk = lg * 8;

    f32x4 acc[4][4] = {};

    for (int k0 = 0; k0 < E_; k0 += 32) {
        #pragma unroll
        for (int p = 0; p < 4; ++p) {
            int flat = p * 256 + tid;
            int c4 = flat & 7, r = flat >> 3;
            float4 v = *(const float4*)&A[(size_t)(bm + r) * E_ + k0 + c4 * 4];
            unsigned short h[4], l[4], q[4];
            split3(v.x, h[0], l[0], q[0]); split3(v.y, h[1], l[1], q[1]);
            split3(v.z, h[2], l[2], q[2]); split3(v.w, h[3], l[3], q[3]);
            unsigned* dh = (unsigned*)&As[0][r][c4 * 4];
            dh[0] = h[0] | ((unsigned)h[1] << 16); dh[1] = h[2] | ((unsigned)h[3] << 16);
            unsigned* dl = (unsigned*)&As[1][r][c4 * 4];
            dl[0] = l[0] | ((unsigned)l[1] << 16); dl[1] = l[2] | ((unsigned)l[3] << 16);
            unsigned* dq = (unsigned*)&As[2][r][c4 * 4];
            dq[0] = q[0] | ((unsigned)q[1] << 16); dq[1] = q[2] | ((unsigned)q[3] << 16);
        }
        #pragma unroll
        for (int p6 = 0; p6 < 6; ++p6) {
            int f = p6 * 256 + tid;
            int pl = f >> 9, rem = f & 511;
            int r = rem >> 2, g4 = rem & 3;
            const unsigned short* src = Bpl + (size_t)pl * (G4_ * E_) + (size_t)(bn + r) * E_ + k0 + g4 * 8;
            *(uint4*)&Bs[pl][r][g4 * 8] = *(const uint4*)src;
        }
        __syncthreads();

        bf16x8 af[3][4], bf[3][4];
        #pragma unroll
        for (int pl = 0; pl < 3; ++pl)
            #pragma unroll
            for (int m = 0; m < 4; ++m) {
                af[pl][m] = *(const bf16x8*)&As[pl][wm * 64 + m * 16 + lr][lk];
                bf[pl][m] = *(const bf16x8*)&Bs[pl][wn * 64 + m * 16 + lr][lk];
            }
        #pragma unroll
        for (int m = 0; m < 4; ++m)
            #pragma unroll
            for (int n = 0; n < 4; ++n) {
                acc[m][n] = __builtin_amdgcn_mfma_f32_16x16x32_bf16(af[0][m], bf[0][n], acc[m][n], 0, 0, 0);
                acc[m][n] = __builtin_amdgcn_mfma_f32_16x16x32_bf16(af[0][m], bf[1][n], acc[m][n], 0, 0, 0);
                acc[m][n] = __builtin_amdgcn_mfma_f32_16x16x32_bf16(af[1][m], bf[0][n], acc[m][n], 0, 0, 0);
                acc[m][n] = __builtin_amdgcn_mfma_f32_16x16x32_bf16(af[1][m], bf[1][n], acc[m][n], 0, 0, 0);
                acc[m][n] = __builtin_amdgcn_mfma_f32_16x16x32_bf16(af[0][m], bf[2][n], acc[m][n], 0, 0, 0);
                acc[m][n] = __builtin_amdgcn_mfma_f32_16x16x32_bf16(af[2][m], bf[0][n], acc[m][n], 0, 0, 0);
            }
        __syncthreads();
    }

    #pragma unroll
    for (int n = 0; n < 4; ++n) {
        int col = bn + wn * 64 + n * 16 + lr;
        float bv = bias1[col] + bias2[col];
        #pragma unroll
        for (int m = 0; m < 4; ++m) {
            int rbase = bm + wm * 64 + m * 16 + lg * 4;
            #pragma unroll
            for (int r = 0; r < 4; ++r) {
                int row = rbase + r;
                Xr[((size_t)(row >> 6) * G4_ + col) * 64 + (row & 63)] = acc[m][n][r] + bv;
            }
        }
    }
}

// ---------------------------------------------------------------------------
// Persistent 128-step LSTM recurrence, 128 blocks x 8 hcols.
// hi+lo weight planes in 128 KB dynamic LDS (XOR-swizzled); q streamed from
// L2 (stays warm: NO cache fences anywhere). u written once per address with
// sc0 sc1 write-through stores (visible at LLC after vmcnt drain); consumers
// use normal cached loads (safe: each u address is written exactly once and
// only read after the relaxed barrier). Barrier: 32 cacheline-spaced
// counters, 4 blocks each, RELAXED add + RELAXED spin, monotone targets.
// ---------------------------------------------------------------------------
__global__ __launch_bounds__(256, 1) void persistent_lstm(
    const float* __restrict__ Xr,              // [128][4096][64]
    const unsigned short* __restrict__ Wpl,    // [3][4096*1024]
    unsigned short* __restrict__ u_ps,         // [129][SLOT]
    unsigned int* bar)                         // 32 counters, 64B apart
{
    extern __shared__ unsigned short smem[];
    unsigned short* Wlds = smem;               // [2pl][2h2][16n][1024] = 131072 B
    unsigned short* u_sm = smem + 65536;       // [3][64][8] = 3072 B

    const int tid = threadIdx.x;
    const int j = blockIdx.x;                  // 0..127
    const int lane = tid & 63, bq = tid >> 6;
    const int lr = lane & 15, lg = lane >> 4;

    // stage hi/lo planes of this block's 32 gate-rows (2 tiles x 16 rows)
    for (int it = 0; it < 32; ++it) {
        int f = it * 256 + tid;                // 0..8191 16B-chunks
        int p = f >> 12;
        int rem = f & 4095;
        int h2 = rem >> 11;
        int rem2 = rem & 2047;
        int n = rem2 >> 7;                     // 0..15
        int g16 = rem2 & 127;                  // 0..127
        int gr = (n & 3) * 1024 + j * 8 + h2 * 4 + (n >> 2);
        const unsigned short* src = Wpl + (size_t)p * (G4_ * H_) + (size_t)gr * H_ + g16 * 8;
        *(uint4*)&Wlds[(size_t)((p * 2 + h2) * 16 + n) * 1024 + (g16 ^ (n & 7)) * 8] = *(const uint4*)src;
    }
    __syncthreads();

    const int b = bq * 16 + lr;
    const int uoff = b * 8;
    const int swzb = lr & 7;
    // q-plane row pointers for the two row-tiles (A-row supplied = lr)
    const unsigned short* wq0 = Wpl + (size_t)2 * (G4_ * H_)
        + (size_t)((lr & 3) * 1024 + j * 8 + 0 + (lr >> 2)) * H_;
    const unsigned short* wq1 = Wpl + (size_t)2 * (G4_ * H_)
        + (size_t)((lr & 3) * 1024 + j * 8 + 4 + (lr >> 2)) * H_;

    float c0 = 0.f, c1 = 0.f;

    for (int t = 0; t < T_; ++t) {
        const unsigned short* ut = u_ps + (size_t)t * SLOT;
        float xg0[4], xg1[4];
        #pragma unroll
        for (int g = 0; g < 4; ++g) {
            xg0[g] = Xr[((size_t)t * G4_ + g * 1024 + j * 8 + lg) * 64 + b];
            xg1[g] = Xr[((size_t)t * G4_ + g * 1024 + j * 8 + 4 + lg) * 64 + b];
        }

        f32x4 a0 = {0.f, 0.f, 0.f, 0.f}, p0 = {0.f, 0.f, 0.f, 0.f};
        f32x4 a1 = {0.f, 0.f, 0.f, 0.f}, p1 = {0.f, 0.f, 0.f, 0.f};
        #pragma unroll 8
        for (int ks = 0; ks < 32; ++ks) {
            int g16 = ks * 4 + lg;
            int swz = (g16 ^ swzb) * 8;
            bf16x8 uh = *(const bf16x8*)&ut[(size_t)g16 * 512 + uoff];
            bf16x8 ul = *(const bf16x8*)&ut[PSTR + (size_t)g16 * 512 + uoff];
            bf16x8 uq = *(const bf16x8*)&ut[2 * PSTR + (size_t)g16 * 512 + uoff];
            bf16x8 wh0 = *(const bf16x8*)&Wlds[(size_t)(0 * 16 + lr) * 1024 + swz];
            bf16x8 wh1 = *(const bf16x8*)&Wlds[(size_t)(1 * 16 + lr) * 1024 + swz];
            bf16x8 wl0 = *(const bf16x8*)&Wlds[(size_t)(2 * 16 + lr) * 1024 + swz];
            bf16x8 wl1 = *(const bf16x8*)&Wlds[(size_t)(3 * 16 + lr) * 1024 + swz];
            bf16x8 wq0v = *(const bf16x8*)&wq0[g16 * 8];
            bf16x8 wq1v = *(const bf16x8*)&wq1[g16 * 8];
            a0 = __builtin_amdgcn_mfma_f32_16x16x32_bf16(wh0, uh, a0, 0, 0, 0);
            a0 = __builtin_amdgcn_mfma_f32_16x16x32_bf16(wh0, ul, a0, 0, 0, 0);
            a0 = __builtin_amdgcn_mfma_f32_16x16x32_bf16(wl0, uh, a0, 0, 0, 0);
            p0 = __builtin_amdgcn_mfma_f32_16x16x32_bf16(wl0, ul, p0, 0, 0, 0);
            p0 = __builtin_amdgcn_mfma_f32_16x16x32_bf16(wh0, uq, p0, 0, 0, 0);
            p0 = __builtin_amdgcn_mfma_f32_16x16x32_bf16(wq0v, uh, p0, 0, 0, 0);
            a1 = __builtin_amdgcn_mfma_f32_16x16x32_bf16(wh1, uh, a1, 0, 0, 0);
            a1 = __builtin_amdgcn_mfma_f32_16x16x32_bf16(wh1, ul, a1, 0, 0, 0);
            a1 = __builtin_amdgcn_mfma_f32_16x16x32_bf16(wl1, uh, a1, 0, 0, 0);
            p1 = __builtin_amdgcn_mfma_f32_16x16x32_bf16(wl1, ul, p1, 0, 0, 0);
            p1 = __builtin_amdgcn_mfma_f32_16x16x32_bf16(wh1, uq, p1, 0, 0, 0);
            p1 = __builtin_amdgcn_mfma_f32_16x16x32_bf16(wq1v, uh, p1, 0, 0, 0);
        }

        {   // tile 0: hcol = j*8 + lg
            float gi = a0[0] + p0[0] + xg0[0];
            float gf = a0[1] + p0[1] + xg0[1];
            float gv = a0[2] + p0[2] + xg0[2];
            float go = a0[3] + p0[3] + xg0[3];
            float si = 1.f / (1.f + __expf(-gi));
            float sf = 1.f / (1.f + __expf(-gf));
            float so = 1.f / (1.f + __expf(-go));
            c0 = sf * c0 + si * tanhf(gv);
            float ho = so * tanhf(c0);
            unsigned short sh, sl, sq;
            split3(ho, sh, sl, sq);
            u_sm[(0 * 64 + b) * 8 + lg] = sh;
            u_sm[(1 * 64 + b) * 8 + lg] = sl;
            u_sm[(2 * 64 + b) * 8 + lg] = sq;
        }
        {   // tile 1: hcol = j*8 + 4 + lg
            float gi = a1[0] + p1[0] + xg1[0];
            float gf = a1[1] + p1[1] + xg1[1];
            float gv = a1[2] + p1[2] + xg1[2];
            float go = a1[3] + p1[3] + xg1[3];
            float si = 1.f / (1.f + __expf(-gi));
            float sf = 1.f / (1.f + __expf(-gf));
            float so = 1.f / (1.f + __expf(-go));
            c1 = sf * c1 + si * tanhf(gv);
            float ho = so * tanhf(c1);
            unsigned short sh, sl, sq;
            split3(ho, sh, sl, sq);
            u_sm[(0 * 64 + b) * 8 + 4 + lg] = sh;
            u_sm[(1 * 64 + b) * 8 + 4 + lg] = sl;
            u_sm[(2 * 64 + b) * 8 + 4 + lg] = sq;
        }
        __syncthreads();                       // u_sm complete

        if (tid < 192) {                       // 3 planes x 64 batches
            int pl = tid >> 6, bb = tid & 63;
            u32x4 v = *(const u32x4*)&u_sm[(pl * 64 + bb) * 8];
            unsigned short* dst = u_ps + (size_t)(t + 1) * SLOT
                                + (size_t)pl * PSTR + (size_t)(j * 64 + bb) * 8;
            asm volatile("global_store_dwordx4 %0, %1, off sc0 sc1"
                         :: "v"(dst), "v"(v) : "memory");
        }
        asm volatile("s_waitcnt vmcnt(0)" ::: "memory");
        __syncthreads();                       // all waves' stores drained

        if (t != T_ - 1) {
            if (tid == 0)
                __hip_atomic_fetch_add(&bar[(j & 31) * 16], 1u,
                                       __ATOMIC_RELAXED, __HIP_MEMORY_SCOPE_AGENT);
            if (tid < 32) {
                const unsigned tgt = (unsigned)(t + 1) * 4u;
                while (__hip_atomic_load(&bar[tid * 16],
                                         __ATOMIC_RELAXED, __HIP_MEMORY_SCOPE_AGENT) < tgt) {}
            }
            __syncthreads();
        }
    }
}

// ---------------------------------------------------------------------------
// Projection GEMM: C(8192,512) = U(8192,1024) @ W_hr^T
// ---------------------------------------------------------------------------
__global__ __launch_bounds__(256) void proj_gemm(
    const unsigned short* __restrict__ u_ps,   // [129][SLOT]
    const float* __restrict__ Whr,             // (512,1024) f32 (N,K)
    float* __restrict__ C)                     // (8192,512)
{
    __shared__ unsigned short Bs[3][128][40];
    const int bn = blockIdx.x * 128;
    const int bm = blockIdx.y * 128;
    const int tid = threadIdx.x;
    const int lane = tid & 63, wid = tid >> 6;
    const int wm = wid >> 1, wn = wid & 1;
    const int lr = lane & 15, lg = lane >> 4, lk = lg * 8;

    f32x4 acc[4][4] = {};
    const int t = (bm >> 6) + wm;
    const unsigned short* ut = u_ps + (size_t)(t + 1) * SLOT;

    for (int k0 = 0; k0 < H_; k0 += 32) {
        #pragma unroll
        for (int p = 0; p < 4; ++p) {
            int flat = p * 256 + tid;
            int c4 = flat & 7, r = flat >> 3;
            float4 v = *(const float4*)&Whr[(size_t)(bn + r) * H_ + k0 + c4 * 4];
            unsigned short h[4], l[4], q[4];
            split3(v.x, h[0], l[0], q[0]); split3(v.y, h[1], l[1], q[1]);
            split3(v.z, h[2], l[2], q[2]); split3(v.w, h[3], l[3], q[3]);
            unsigned* dh = (unsigned*)&Bs[0][r][c4 * 4];
            dh[0] = h[0] | ((unsigned)h[1] << 16); dh[1] = h[2] | ((unsigned)h[3] << 16);
            unsigned* dl = (unsigned*)&Bs[1][r][c4 * 4];
            dl[0] = l[0] | ((unsigned)l[1] << 16); dl[1] = l[2] | ((unsigned)l[3] << 16);
            unsigned* dq = (unsigned*)&Bs[2][r][c4 * 4];
            dq[0] = q[0] | ((unsigned)q[1] << 16); dq[1] = q[2] | ((unsigned)q[3] << 16);
        }
        __syncthreads();

        int ks = k0 >> 5;
        bf16x8 af[3][4], bf[3][4];
        #pragma unroll
        for (int pl = 0; pl < 3; ++pl)
            #pragma unroll
            for (int m = 0; m < 4; ++m) {
                af[pl][m] = *(const bf16x8*)&ut[(size_t)pl * PSTR + (size_t)((ks * 4 + lg) * 64 + m * 16 + lr) * 8];
                bf[pl][m] = *(const bf16x8*)&Bs[pl][wn * 64 + m * 16 + lr][lk];
            }
        #pragma unroll
        for (int m = 0; m < 4; ++m)
            #pragma unroll
            for (int n = 0; n < 4; ++n) {
                acc[m][n] = __builtin_amdgcn_mfma_f32_16x16x32_bf16(af[0][m], bf[0][n], acc[m][n], 0, 0, 0);
                acc[m][n] = __builtin_amdgcn_mfma_f32_16x16x32_bf16(af[0][m], bf[1][n], acc[m][n], 0, 0, 0);
                acc[m][n] = __builtin_amdgcn_mfma_f32_16x16x32_bf16(af[1][m], bf[0][n], acc[m][n], 0, 0, 0);
                acc[m][n] = __builtin_amdgcn_mfma_f32_16x16x32_bf16(af[1][m], bf[1][n], acc[m][n], 0, 0, 0);
                acc[m][n] = __builtin_amdgcn_mfma_f32_16x16x32_bf16(af[0][m], bf[2][n], acc[m][n], 0, 0, 0);
                acc[m][n] = __builtin_amdgcn_mfma_f32_16x16x32_bf16(af[2][m], bf[0][n], acc[m][n], 0, 0, 0);
            }
        __syncthreads();
    }

    #pragma unroll
    for (int m = 0; m < 4; ++m) {
        int rbase = bm + wm * 64 + m * 16 + lg * 4;
        #pragma unroll
        for (int n = 0; n < 4; ++n) {
            int col = bn + wn * 64 + n * 16 + lr;
            #pragma unroll
            for (int r = 0; r < 4; ++r)
                C[(size_t)(rbase + r) * E_ + col] = acc[m][n][r];
        }
    }
}

// ---------------------------------------------------------------------------
// Row softmax over E=512; input rows m = t*64+b, output row (b, t).
// ---------------------------------------------------------------------------
__global__ __launch_bounds__(256) void softmax_kernel(
    const float* __restrict__ LOG, float* __restrict__ out)
{
    const int lane = threadIdx.x & 63;
    const int r = blockIdx.x * 4 + (threadIdx.x >> 6);
    const float* src = LOG + (size_t)r * E_;
    float v[8];
    *(float4*)&v[0] = ((const float4*)src)[lane * 2];
    *(float4*)&v[4] = ((const float4*)src)[lane * 2 + 1];

    float m = v[0];
    #pragma unroll
    for (int i = 1; i < 8; ++i) m = fmaxf(m, v[i]);
    #pragma unroll
    for (int off = 32; off > 0; off >>= 1) m = fmaxf(m, __shfl_xor(m, off, 64));

    float s = 0.f;
    #pragma unroll
    for (int i = 0; i < 8; ++i) { v[i] = expf(v[i] - m); s += v[i]; }
    #pragma unroll
    for (int off = 32; off > 0; off >>= 1) s += __shfl_xor(s, off, 64);
    const float inv = 1.f / s;

    const int t = r >> 6, b = r & 63;
    float* dst = out + ((size_t)b * T_ + t) * E_;
    #pragma unroll
    for (int i = 0; i < 8; ++i) v[i] *= inv;
    ((float4*)dst)[lane * 2]     = *(float4*)&v[0];
    ((float4*)dst)[lane * 2 + 1] = *(float4*)&v[4];
}

// ---------------------------------------------------------------------------
extern "C" void kernel_launch(void* const* d_in, const int* in_sizes, int n_in,
                              void* d_out, int out_size, void* d_ws, size_t ws_size,
                              hipStream_t stream)
{
    const float* images   = (const float*)d_in[0];
    const int*   captions = (const int*)  d_in[1];
    const float* table    = (const float*)d_in[2];
    const float* W_ih     = (const float*)d_in[3];
    const float* W_hh     = (const float*)d_in[4];
    const float* W_hr     = (const float*)d_in[5];
    const float* b_ih     = (const float*)d_in[6];
    const float* b_hh     = (const float*)d_in[7];
    float* out = (float*)d_out;

    // Workspace layout (bytes)
    char* base = (char*)d_ws;
    float*          Xr      = (float*)base;                               // 134,217,728
    unsigned int*   bar     = (unsigned int*)(base + 134217728);          //       4,096
    unsigned short* u_ps    = (unsigned short*)(base + 134221824);        //  50,724,864
    unsigned short* WhhrPl  = (unsigned short*)(base + 184946688);        //  25,165,824
    float*          seq     = (float*)(base + 210112512);                 //  16,777,216
    // aliases (sequentially dead regions)
    float*          WhhrF32 = (float*)((char*)u_ps + 786432);
    unsigned short* WihPl   = (unsigned short*)((char*)u_ps + 786432);
    float*          logits  = Xr;
    float*          H0      = seq;

    const int SMEM_BYTES = 131072 + 3072;   // Wlds + u_sm
    (void)hipFuncSetAttribute((const void*)persistent_lstm,
                              hipFuncAttributeMaxDynamicSharedMemorySize, SMEM_BYTES);

    embed_kernel<<<T_ * B_, 128, 0, stream>>>(images, captions, table, seq);

    for (int l = 0; l < L_; ++l) {
        const float* wih = W_ih + (size_t)l * G4_ * E_;
        const float* whh = W_hh + (size_t)l * G4_ * E_;
        const float* whr = W_hr + (size_t)l * E_ * H_;
        const float* bih = b_ih + (size_t)l * G4_;
        const float* bhh = b_hh + (size_t)l * G4_;

        // Whhr = W_hh (4096,512) @ W_hr (512,1024), f32 (scratch inside u_ps)
        mfma_gemm<false><<<dim3(H_ / 128, G4_ / 128), 256, 0, stream>>>(
            whh, whr, WhhrF32, G4_, H_, E_, nullptr, nullptr);
        split_planes<<<(G4_ * H_) / 1024, 256, 0, stream>>>(WhhrF32, WhhrPl, (size_t)G4_ * H_);
        split_planes<<<(G4_ * E_) / 1024, 256, 0, stream>>>(wih, WihPl, (size_t)G4_ * E_);

        // X = inp @ W_ih^T + b_ih + b_hh, stored [t][col][b]
        const float* inp = (l == 0) ? seq : H0;
        xgemm_kernel<<<dim3(G4_ / 128, (T_ * B_) / 128), 256, 0, stream>>>(
            inp, WihPl, bih, bhh, Xr);

        // zero u(0) and barrier state
        (void)hipMemsetAsync(u_ps, 0, SLOT * sizeof(unsigned short), stream);
        (void)hipMemsetAsync(bar, 0, 4096, stream);

        // 128-step recurrence, one cooperative launch (residency guarantee)
        {
            const float* xr_a = Xr;
            const unsigned short* wpl_a = WhhrPl;
            unsigned short* ups_a = u_ps;
            unsigned int* bar_a = bar;
            void* args[] = { (void*)&xr_a, (void*)&wpl_a, (void*)&ups_a, (void*)&bar_a };
            (void)hipLaunchCooperativeKernel((const void*)persistent_lstm,
                                             dim3(128), dim3(256), args, SMEM_BYTES, stream);
        }

        // project all u -> H0 (layer 0) or logits (layer 1)
        float* pdst = (l == 0) ? H0 : logits;
        proj_gemm<<<dim3(E_ / 128, (T_ * B_) / 128), 256, 0, stream>>>(u_ps, whr, pdst);
    }

    softmax_kernel<<<(T_ * B_) / 4, 256, 0, stream>>>(logits, out);

    (void)in_sizes; (void)n_in; (void)out_size; (void)ws_size;
}

// Round 7
// 5304.565 us; speedup vs baseline: 2.1105x; 1.0049x over previous
//
#include <hip/hip_runtime.h>
#include <cstdint>
#include <cstddef>

// Problem constants
#define V_ 10000
#define E_ 512
#define H_ 1024
#define L_ 2
#define B_ 64
#define T_ 128
#define G4_ (4 * H_)                 // 4096 gate width
#define SLOT (3 * 128 * 64 * 8)      // shorts per u_ps timestep slot (3 planes)
#define PSTR 65536                   // shorts per u_ps plane (128*64*8)

typedef __attribute__((ext_vector_type(8))) short bf16x8;
typedef __attribute__((ext_vector_type(4))) float f32x4;
typedef __attribute__((ext_vector_type(4))) unsigned int u32x4;

// ---------------------------------------------------------------------------
// bf16 split helpers (RNE; finite values only)
// ---------------------------------------------------------------------------
__device__ __forceinline__ unsigned short f2b(float x) {
    unsigned u = __float_as_uint(x);
    unsigned r = (u + 0x7FFFu + ((u >> 16) & 1u)) >> 16;
    return (unsigned short)r;
}
__device__ __forceinline__ float b2f(unsigned short h) {
    return __uint_as_float(((unsigned)h) << 16);
}
__device__ __forceinline__ void split3(float a, unsigned short& h, unsigned short& l, unsigned short& q) {
    h = f2b(a); float r = a - b2f(h);
    l = f2b(r); float r2 = r - b2f(l);
    q = f2b(r2);
}

// ---------------------------------------------------------------------------
// Embedding + concat: seq (T, B, E) rows m = t*64 + b
// ---------------------------------------------------------------------------
__global__ __launch_bounds__(128) void embed_kernel(
    const float* __restrict__ images, const int* __restrict__ captions,
    const float* __restrict__ table, float* __restrict__ seq)
{
    const int m = blockIdx.x;            // 0..8191
    const int t = m >> 6, b = m & 63;
    const float* src;
    if (t == 0) src = images + (size_t)b * E_;
    else        src = table + (size_t)captions[b * T_ + (t - 1)] * E_;
    float4 v = ((const float4*)src)[threadIdx.x];
    ((float4*)(seq + (size_t)m * E_))[threadIdx.x] = v;
}

// ---------------------------------------------------------------------------
// f32 -> 3 bf16 plane split (plane stride = n elements)
// ---------------------------------------------------------------------------
__global__ __launch_bounds__(256) void split_planes(
    const float* __restrict__ in, unsigned short* __restrict__ pl, size_t n)
{
    size_t i = ((size_t)blockIdx.x * 256 + threadIdx.x) * 4;
    if (i >= n) return;
    float4 v = *(const float4*)&in[i];
    unsigned short h[4], l[4], q[4];
    split3(v.x, h[0], l[0], q[0]); split3(v.y, h[1], l[1], q[1]);
    split3(v.z, h[2], l[2], q[2]); split3(v.w, h[3], l[3], q[3]);
    ushort4 hv = {h[0], h[1], h[2], h[3]};
    ushort4 lv = {l[0], l[1], l[2], l[3]};
    ushort4 qv = {q[0], q[1], q[2], q[3]};
    *(ushort4*)&pl[i]         = hv;
    *(ushort4*)&pl[n + i]     = lv;
    *(ushort4*)&pl[2 * n + i] = qv;
}

// ---------------------------------------------------------------------------
// Split-bf16x6 MFMA GEMM, in-kernel split of both operands.
// Used only for Whhr = W_hh @ W_hr (K,N f32 B). C = A(M,K) @ B(K,N), f32 out.
// ---------------------------------------------------------------------------
template<bool BNK>
__global__ __launch_bounds__(256) void mfma_gemm(
    const float* __restrict__ A, const float* __restrict__ Bm, float* __restrict__ C,
    int M, int N, int K,
    const float* __restrict__ bias1, const float* __restrict__ bias2)
{
    __shared__ unsigned short As[3][128][40];
    __shared__ unsigned short Bs[3][128][40];
    const int bm = blockIdx.y * 128, bn = blockIdx.x * 128;
    const int tid = threadIdx.x;
    const int lane = tid & 63, wid = tid >> 6;
    const int wm = wid >> 1, wn = wid & 1;
    const int lr = lane & 15, lk = (lane >> 4) * 8;

    f32x4 acc[4][4] = {};

    for (int k0 = 0; k0 < K; k0 += 32) {
        #pragma unroll
        for (int p = 0; p < 4; ++p) {
            int flat = p * 256 + tid;
            int c4 = flat & 7, r = flat >> 3;
            float4 v = *(const float4*)&A[(size_t)(bm + r) * K + k0 + c4 * 4];
            unsigned short h[4], l[4], q[4];
            split3(v.x, h[0], l[0], q[0]); split3(v.y, h[1], l[1], q[1]);
            split3(v.z, h[2], l[2], q[2]); split3(v.w, h[3], l[3], q[3]);
            unsigned* dh = (unsigned*)&As[0][r][c4 * 4];
            dh[0] = h[0] | ((unsigned)h[1] << 16); dh[1] = h[2] | ((unsigned)h[3] << 16);
            unsigned* dl = (unsigned*)&As[1][r][c4 * 4];
            dl[0] = l[0] | ((unsigned)l[1] << 16); dl[1] = l[2] | ((unsigned)l[3] << 16);
            unsigned* dq = (unsigned*)&As[2][r][c4 * 4];
            dq[0] = q[0] | ((unsigned)q[1] << 16); dq[1] = q[2] | ((unsigned)q[3] << 16);
        }
        if (BNK) {
            #pragma unroll
            for (int p = 0; p < 4; ++p) {
                int flat = p * 256 + tid;
                int c4 = flat & 7, r = flat >> 3;
                float4 v = *(const float4*)&Bm[(size_t)(bn + r) * K + k0 + c4 * 4];
                unsigned short h[4], l[4], q[4];
                split3(v.x, h[0], l[0], q[0]); split3(v.y, h[1], l[1], q[1]);
                split3(v.z, h[2], l[2], q[2]); split3(v.w, h[3], l[3], q[3]);
                unsigned* dh = (unsigned*)&Bs[0][r][c4 * 4];
                dh[0] = h[0] | ((unsigned)h[1] << 16); dh[1] = h[2] | ((unsigned)h[3] << 16);
                unsigned* dl = (unsigned*)&Bs[1][r][c4 * 4];
                dl[0] = l[0] | ((unsigned)l[1] << 16); dl[1] = l[2] | ((unsigned)l[3] << 16);
                unsigned* dq = (unsigned*)&Bs[2][r][c4 * 4];
                dq[0] = q[0] | ((unsigned)q[1] << 16); dq[1] = q[2] | ((unsigned)q[3] << 16);
            }
        } else {
            #pragma unroll
            for (int p = 0; p < 4; ++p) {
                int flat = p * 256 + tid;
                int n4 = flat & 31, kr = flat >> 5;
                float4 v = *(const float4*)&Bm[(size_t)(k0 + kr) * N + bn + n4 * 4];
                float vv[4] = {v.x, v.y, v.z, v.w};
                #pragma unroll
                for (int jj = 0; jj < 4; ++jj) {
                    unsigned short h, l, q; split3(vv[jj], h, l, q);
                    Bs[0][n4 * 4 + jj][kr] = h;
                    Bs[1][n4 * 4 + jj][kr] = l;
                    Bs[2][n4 * 4 + jj][kr] = q;
                }
            }
        }
        __syncthreads();

        bf16x8 af[3][4], bf[3][4];
        #pragma unroll
        for (int pl = 0; pl < 3; ++pl)
            #pragma unroll
            for (int m = 0; m < 4; ++m) {
                af[pl][m] = *(const bf16x8*)&As[pl][wm * 64 + m * 16 + lr][lk];
                bf[pl][m] = *(const bf16x8*)&Bs[pl][wn * 64 + m * 16 + lr][lk];
            }
        #pragma unroll
        for (int m = 0; m < 4; ++m)
            #pragma unroll
            for (int n = 0; n < 4; ++n) {
                acc[m][n] = __builtin_amdgcn_mfma_f32_16x16x32_bf16(af[0][m], bf[0][n], acc[m][n], 0, 0, 0);
                acc[m][n] = __builtin_amdgcn_mfma_f32_16x16x32_bf16(af[0][m], bf[1][n], acc[m][n], 0, 0, 0);
                acc[m][n] = __builtin_amdgcn_mfma_f32_16x16x32_bf16(af[1][m], bf[0][n], acc[m][n], 0, 0, 0);
                acc[m][n] = __builtin_amdgcn_mfma_f32_16x16x32_bf16(af[1][m], bf[1][n], acc[m][n], 0, 0, 0);
                acc[m][n] = __builtin_amdgcn_mfma_f32_16x16x32_bf16(af[0][m], bf[2][n], acc[m][n], 0, 0, 0);
                acc[m][n] = __builtin_amdgcn_mfma_f32_16x16x32_bf16(af[2][m], bf[0][n], acc[m][n], 0, 0, 0);
            }
        __syncthreads();
    }

    float bv[4];
    #pragma unroll
    for (int n = 0; n < 4; ++n) {
        int col = bn + wn * 64 + n * 16 + lr;
        float x = 0.f;
        if (bias1) x += bias1[col];
        if (bias2) x += bias2[col];
        bv[n] = x;
    }
    #pragma unroll
    for (int m = 0; m < 4; ++m) {
        int rbase = bm + wm * 64 + m * 16 + (lane >> 4) * 4;
        #pragma unroll
        for (int n = 0; n < 4; ++n) {
            int col = bn + wn * 64 + n * 16 + lr;
            #pragma unroll
            for (int r = 0; r < 4; ++r)
                C[(size_t)(rbase + r) * N + col] = acc[m][n][r] + bv[n];
        }
    }
}

// ---------------------------------------------------------------------------
// X GEMM: Xr[t][col][b] = (seq/H0)(8192,512) @ W_ih^T + b_ih + b_hh
// ---------------------------------------------------------------------------
__global__ __launch_bounds__(256) void xgemm_kernel(
    const float* __restrict__ A, const unsigned short* __restrict__ Bpl,
    const float* __restrict__ bias1, const float* __restrict__ bias2,
    float* __restrict__ Xr)
{
    __shared__ unsigned short As[3][128][40];
    __shared__ unsigned short Bs[3][128][40];
    const int bm = blockIdx.y * 128, bn = blockIdx.x * 128;
    const int tid = threadIdx.x;
    const int lane = tid & 63, wid = tid >> 6;
    const int wm = wid >> 1, wn = wid & 1;
    const int lr = lane & 15, lg = lane >> 4, lk = lg * 8;

    f32x4 acc[4][4] = {};

    for (int k0 = 0; k0 < E_; k0 += 32) {
        #pragma unroll
        for (int p = 0; p < 4; ++p) {
            int flat = p * 256 + tid;
            int c4 = flat & 7, r = flat >> 3;
            float4 v = *(const float4*)&A[(size_t)(bm + r) * E_ + k0 + c4 * 4];
            unsigned short h[4], l[4], q[4];
            split3(v.x, h[0], l[0], q[0]); split3(v.y, h[1], l[1], q[1]);
            split3(v.z, h[2], l[2], q[2]); split3(v.w, h[3], l[3], q[3]);
            unsigned* dh = (unsigned*)&As[0][r][c4 * 4];
            dh[0] = h[0] | ((unsigned)h[1] << 16); dh[1] = h[2] | ((unsigned)h[3] << 16);
            unsigned* dl = (unsigned*)&As[1][r][c4 * 4];
            dl[0] = l[0] | ((unsigned)l[1] << 16); dl[1] = l[2] | ((unsigned)l[3] << 16);
            unsigned* dq = (unsigned*)&As[2][r][c4 * 4];
            dq[0] = q[0] | ((unsigned)q[1] << 16); dq[1] = q[2] | ((unsigned)q[3] << 16);
        }
        #pragma unroll
        for (int p6 = 0; p6 < 6; ++p6) {
            int f = p6 * 256 + tid;
            int pl = f >> 9, rem = f & 511;
            int r = rem >> 2, g4 = rem & 3;
            const unsigned short* src = Bpl + (size_t)pl * (G4_ * E_) + (size_t)(bn + r) * E_ + k0 + g4 * 8;
            *(uint4*)&Bs[pl][r][g4 * 8] = *(const uint4*)src;
        }
        __syncthreads();

        bf16x8 af[3][4], bf[3][4];
        #pragma unroll
        for (int pl = 0; pl < 3; ++pl)
            #pragma unroll
            for (int m = 0; m < 4; ++m) {
                af[pl][m] = *(const bf16x8*)&As[pl][wm * 64 + m * 16 + lr][lk];
                bf[pl][m] = *(const bf16x8*)&Bs[pl][wn * 64 + m * 16 + lr][lk];
            }
        #pragma unroll
        for (int m = 0; m < 4; ++m)
            #pragma unroll
            for (int n = 0; n < 4; ++n) {
                acc[m][n] = __builtin_amdgcn_mfma_f32_16x16x32_bf16(af[0][m], bf[0][n], acc[m][n], 0, 0, 0);
                acc[m][n] = __builtin_amdgcn_mfma_f32_16x16x32_bf16(af[0][m], bf[1][n], acc[m][n], 0, 0, 0);
                acc[m][n] = __builtin_amdgcn_mfma_f32_16x16x32_bf16(af[1][m], bf[0][n], acc[m][n], 0, 0, 0);
                acc[m][n] = __builtin_amdgcn_mfma_f32_16x16x32_bf16(af[1][m], bf[1][n], acc[m][n], 0, 0, 0);
                acc[m][n] = __builtin_amdgcn_mfma_f32_16x16x32_bf16(af[0][m], bf[2][n], acc[m][n], 0, 0, 0);
                acc[m][n] = __builtin_amdgcn_mfma_f32_16x16x32_bf16(af[2][m], bf[0][n], acc[m][n], 0, 0, 0);
            }
        __syncthreads();
    }

    #pragma unroll
    for (int n = 0; n < 4; ++n) {
        int col = bn + wn * 64 + n * 16 + lr;
        float bv = bias1[col] + bias2[col];
        #pragma unroll
        for (int m = 0; m < 4; ++m) {
            int rbase = bm + wm * 64 + m * 16 + lg * 4;
            #pragma unroll
            for (int r = 0; r < 4; ++r) {
                int row = rbase + r;
                Xr[((size_t)(row >> 6) * G4_ + col) * 64 + (row & 63)] = acc[m][n][r] + bv;
            }
        }
    }
}

// ---------------------------------------------------------------------------
// Persistent 128-step LSTM recurrence, 128 blocks x 8 hcols.
// hi+lo weight planes in 128 KB dynamic LDS (XOR-swizzled); q streamed from
// L2 (stays warm: NO cache fences anywhere). u written once per address with
// sc0 sc1 write-through stores (visible at LLC after vmcnt drain); consumers
// use normal cached loads (safe: each u address is written exactly once and
// only read after the relaxed barrier). Barrier: 32 cacheline-spaced
// counters, 4 blocks each, RELAXED add + RELAXED spin, monotone targets.
// ---------------------------------------------------------------------------
__global__ __launch_bounds__(256, 1) void persistent_lstm(
    const float* __restrict__ Xr,              // [128][4096][64]
    const unsigned short* __restrict__ Wpl,    // [3][4096*1024]
    unsigned short* __restrict__ u_ps,         // [129][SLOT]
    unsigned int* bar)                         // 32 counters, 64B apart
{
    extern __shared__ unsigned short smem[];
    unsigned short* Wlds = smem;               // [2pl][2h2][16n][1024] = 131072 B
    unsigned short* u_sm = smem + 65536;       // [3][64][8] = 3072 B

    const int tid = threadIdx.x;
    const int j = blockIdx.x;                  // 0..127
    const int lane = tid & 63, bq = tid >> 6;
    const int lr = lane & 15, lg = lane >> 4;

    // stage hi/lo planes of this block's 32 gate-rows (2 tiles x 16 rows)
    for (int it = 0; it < 32; ++it) {
        int f = it * 256 + tid;                // 0..8191 16B-chunks
        int p = f >> 12;
        int rem = f & 4095;
        int h2 = rem >> 11;
        int rem2 = rem & 2047;
        int n = rem2 >> 7;                     // 0..15
        int g16 = rem2 & 127;                  // 0..127
        int gr = (n & 3) * 1024 + j * 8 + h2 * 4 + (n >> 2);
        const unsigned short* src = Wpl + (size_t)p * (G4_ * H_) + (size_t)gr * H_ + g16 * 8;
        *(uint4*)&Wlds[(size_t)((p * 2 + h2) * 16 + n) * 1024 + (g16 ^ (n & 7)) * 8] = *(const uint4*)src;
    }
    __syncthreads();

    const int b = bq * 16 + lr;
    const int uoff = b * 8;
    const int swzb = lr & 7;
    // q-plane row pointers for the two row-tiles (A-row supplied = lr)
    const unsigned short* wq0 = Wpl + (size_t)2 * (G4_ * H_)
        + (size_t)((lr & 3) * 1024 + j * 8 + 0 + (lr >> 2)) * H_;
    const unsigned short* wq1 = Wpl + (size_t)2 * (G4_ * H_)
        + (size_t)((lr & 3) * 1024 + j * 8 + 4 + (lr >> 2)) * H_;

    float c0 = 0.f, c1 = 0.f;

    for (int t = 0; t < T_; ++t) {
        const unsigned short* ut = u_ps + (size_t)t * SLOT;
        float xg0[4], xg1[4];
        #pragma unroll
        for (int g = 0; g < 4; ++g) {
            xg0[g] = Xr[((size_t)t * G4_ + g * 1024 + j * 8 + lg) * 64 + b];
            xg1[g] = Xr[((size_t)t * G4_ + g * 1024 + j * 8 + 4 + lg) * 64 + b];
        }

        f32x4 a0 = {0.f, 0.f, 0.f, 0.f}, p0 = {0.f, 0.f, 0.f, 0.f};
        f32x4 a1 = {0.f, 0.f, 0.f, 0.f}, p1 = {0.f, 0.f, 0.f, 0.f};
        #pragma unroll 8
        for (int ks = 0; ks < 32; ++ks) {
            int g16 = ks * 4 + lg;
            int swz = (g16 ^ swzb) * 8;
            bf16x8 uh = *(const bf16x8*)&ut[(size_t)g16 * 512 + uoff];
            bf16x8 ul = *(const bf16x8*)&ut[PSTR + (size_t)g16 * 512 + uoff];
            bf16x8 uq = *(const bf16x8*)&ut[2 * PSTR + (size_t)g16 * 512 + uoff];
            bf16x8 wh0 = *(const bf16x8*)&Wlds[(size_t)(0 * 16 + lr) * 1024 + swz];
            bf16x8 wh1 = *(const bf16x8*)&Wlds[(size_t)(1 * 16 + lr) * 1024 + swz];
            bf16x8 wl0 = *(const bf16x8*)&Wlds[(size_t)(2 * 16 + lr) * 1024 + swz];
            bf16x8 wl1 = *(const bf16x8*)&Wlds[(size_t)(3 * 16 + lr) * 1024 + swz];
            bf16x8 wq0v = *(const bf16x8*)&wq0[g16 * 8];
            bf16x8 wq1v = *(const bf16x8*)&wq1[g16 * 8];
            a0 = __builtin_amdgcn_mfma_f32_16x16x32_bf16(wh0, uh, a0, 0, 0, 0);
            a0 = __builtin_amdgcn_mfma_f32_16x16x32_bf16(wh0, ul, a0, 0, 0, 0);
            a0 = __builtin_amdgcn_mfma_f32_16x16x32_bf16(wl0, uh, a0, 0, 0, 0);
            p0 = __builtin_amdgcn_mfma_f32_16x16x32_bf16(wl0, ul, p0, 0, 0, 0);
            p0 = __builtin_amdgcn_mfma_f32_16x16x32_bf16(wh0, uq, p0, 0, 0, 0);
            p0 = __builtin_amdgcn_mfma_f32_16x16x32_bf16(wq0v, uh, p0, 0, 0, 0);
            a1 = __builtin_amdgcn_mfma_f32_16x16x32_bf16(wh1, uh, a1, 0, 0, 0);
            a1 = __builtin_amdgcn_mfma_f32_16x16x32_bf16(wh1, ul, a1, 0, 0, 0);
            a1 = __builtin_amdgcn_mfma_f32_16x16x32_bf16(wl1, uh, a1, 0, 0, 0);
            p1 = __builtin_amdgcn_mfma_f32_16x16x32_bf16(wl1, ul, p1, 0, 0, 0);
            p1 = __builtin_amdgcn_mfma_f32_16x16x32_bf16(wh1, uq, p1, 0, 0, 0);
            p1 = __builtin_amdgcn_mfma_f32_16x16x32_bf16(wq1v, uh, p1, 0, 0, 0);
        }

        {   // tile 0: hcol = j*8 + lg
            float gi = a0[0] + p0[0] + xg0[0];
            float gf = a0[1] + p0[1] + xg0[1];
            float gv = a0[2] + p0[2] + xg0[2];
            float go = a0[3] + p0[3] + xg0[3];
            float si = 1.f / (1.f + __expf(-gi));
            float sf = 1.f / (1.f + __expf(-gf));
            float so = 1.f / (1.f + __expf(-go));
            c0 = sf * c0 + si * tanhf(gv);
            float ho = so * tanhf(c0);
            unsigned short sh, sl, sq;
            split3(ho, sh, sl, sq);
            u_sm[(0 * 64 + b) * 8 + lg] = sh;
            u_sm[(1 * 64 + b) * 8 + lg] = sl;
            u_sm[(2 * 64 + b) * 8 + lg] = sq;
        }
        {   // tile 1: hcol = j*8 + 4 + lg
            float gi = a1[0] + p1[0] + xg1[0];
            float gf = a1[1] + p1[1] + xg1[1];
            float gv = a1[2] + p1[2] + xg1[2];
            float go = a1[3] + p1[3] + xg1[3];
            float si = 1.f / (1.f + __expf(-gi));
            float sf = 1.f / (1.f + __expf(-gf));
            float so = 1.f / (1.f + __expf(-go));
            c1 = sf * c1 + si * tanhf(gv);
            float ho = so * tanhf(c1);
            unsigned short sh, sl, sq;
            split3(ho, sh, sl, sq);
            u_sm[(0 * 64 + b) * 8 + 4 + lg] = sh;
            u_sm[(1 * 64 + b) * 8 + 4 + lg] = sl;
            u_sm[(2 * 64 + b) * 8 + 4 + lg] = sq;
        }
        __syncthreads();                       // u_sm complete

        if (tid < 192) {                       // 3 planes x 64 batches
            int pl = tid >> 6, bb = tid & 63;
            u32x4 v = *(const u32x4*)&u_sm[(pl * 64 + bb) * 8];
            unsigned short* dst = u_ps + (size_t)(t + 1) * SLOT
                                + (size_t)pl * PSTR + (size_t)(j * 64 + bb) * 8;
            asm volatile("global_store_dwordx4 %0, %1, off sc0 sc1"
                         :: "v"(dst), "v"(v) : "memory");
        }
        asm volatile("s_waitcnt vmcnt(0)" ::: "memory");
        __syncthreads();                       // all waves' stores drained

        if (t != T_ - 1) {
            if (tid == 0)
                __hip_atomic_fetch_add(&bar[(j & 31) * 16], 1u,
                                       __ATOMIC_RELAXED, __HIP_MEMORY_SCOPE_AGENT);
            if (tid < 32) {
                const unsigned tgt = (unsigned)(t + 1) * 4u;
                while (__hip_atomic_load(&bar[tid * 16],
                                         __ATOMIC_RELAXED, __HIP_MEMORY_SCOPE_AGENT) < tgt) {}
            }
            __syncthreads();
        }
    }
}

// ---------------------------------------------------------------------------
// Projection GEMM: C(8192,512) = U(8192,1024) @ W_hr^T
// ---------------------------------------------------------------------------
__global__ __launch_bounds__(256) void proj_gemm(
    const unsigned short* __restrict__ u_ps,   // [129][SLOT]
    const float* __restrict__ Whr,             // (512,1024) f32 (N,K)
    float* __restrict__ C)                     // (8192,512)
{
    __shared__ unsigned short Bs[3][128][40];
    const int bn = blockIdx.x * 128;
    const int bm = blockIdx.y * 128;
    const int tid = threadIdx.x;
    const int lane = tid & 63, wid = tid >> 6;
    const int wm = wid >> 1, wn = wid & 1;
    const int lr = lane & 15, lg = lane >> 4, lk = lg * 8;

    f32x4 acc[4][4] = {};
    const int t = (bm >> 6) + wm;
    const unsigned short* ut = u_ps + (size_t)(t + 1) * SLOT;

    for (int k0 = 0; k0 < H_; k0 += 32) {
        #pragma unroll
        for (int p = 0; p < 4; ++p) {
            int flat = p * 256 + tid;
            int c4 = flat & 7, r = flat >> 3;
            float4 v = *(const float4*)&Whr[(size_t)(bn + r) * H_ + k0 + c4 * 4];
            unsigned short h[4], l[4], q[4];
            split3(v.x, h[0], l[0], q[0]); split3(v.y, h[1], l[1], q[1]);
            split3(v.z, h[2], l[2], q[2]); split3(v.w, h[3], l[3], q[3]);
            unsigned* dh = (unsigned*)&Bs[0][r][c4 * 4];
            dh[0] = h[0] | ((unsigned)h[1] << 16); dh[1] = h[2] | ((unsigned)h[3] << 16);
            unsigned* dl = (unsigned*)&Bs[1][r][c4 * 4];
            dl[0] = l[0] | ((unsigned)l[1] << 16); dl[1] = l[2] | ((unsigned)l[3] << 16);
            unsigned* dq = (unsigned*)&Bs[2][r][c4 * 4];
            dq[0] = q[0] | ((unsigned)q[1] << 16); dq[1] = q[2] | ((unsigned)q[3] << 16);
        }
        __syncthreads();

        int ks = k0 >> 5;
        bf16x8 af[3][4], bf[3][4];
        #pragma unroll
        for (int pl = 0; pl < 3; ++pl)
            #pragma unroll
            for (int m = 0; m < 4; ++m) {
                af[pl][m] = *(const bf16x8*)&ut[(size_t)pl * PSTR + (size_t)((ks * 4 + lg) * 64 + m * 16 + lr) * 8];
                bf[pl][m] = *(const bf16x8*)&Bs[pl][wn * 64 + m * 16 + lr][lk];
            }
        #pragma unroll
        for (int m = 0; m < 4; ++m)
            #pragma unroll
            for (int n = 0; n < 4; ++n) {
                acc[m][n] = __builtin_amdgcn_mfma_f32_16x16x32_bf16(af[0][m], bf[0][n], acc[m][n], 0, 0, 0);
                acc[m][n] = __builtin_amdgcn_mfma_f32_16x16x32_bf16(af[0][m], bf[1][n], acc[m][n], 0, 0, 0);
                acc[m][n] = __builtin_amdgcn_mfma_f32_16x16x32_bf16(af[1][m], bf[0][n], acc[m][n], 0, 0, 0);
                acc[m][n] = __builtin_amdgcn_mfma_f32_16x16x32_bf16(af[1][m], bf[1][n], acc[m][n], 0, 0, 0);
                acc[m][n] = __builtin_amdgcn_mfma_f32_16x16x32_bf16(af[0][m], bf[2][n], acc[m][n], 0, 0, 0);
                acc[m][n] = __builtin_amdgcn_mfma_f32_16x16x32_bf16(af[2][m], bf[0][n], acc[m][n], 0, 0, 0);
            }
        __syncthreads();
    }

    #pragma unroll
    for (int m = 0; m < 4; ++m) {
        int rbase = bm + wm * 64 + m * 16 + lg * 4;
        #pragma unroll
        for (int n = 0; n < 4; ++n) {
            int col = bn + wn * 64 + n * 16 + lr;
            #pragma unroll
            for (int r = 0; r < 4; ++r)
                C[(size_t)(rbase + r) * E_ + col] = acc[m][n][r];
        }
    }
}

// ---------------------------------------------------------------------------
// Row softmax over E=512; input rows m = t*64+b, output row (b, t).
// ---------------------------------------------------------------------------
__global__ __launch_bounds__(256) void softmax_kernel(
    const float* __restrict__ LOG, float* __restrict__ out)
{
    const int lane = threadIdx.x & 63;
    const int r = blockIdx.x * 4 + (threadIdx.x >> 6);
    const float* src = LOG + (size_t)r * E_;
    float v[8];
    *(float4*)&v[0] = ((const float4*)src)[lane * 2];
    *(float4*)&v[4] = ((const float4*)src)[lane * 2 + 1];

    float m = v[0];
    #pragma unroll
    for (int i = 1; i < 8; ++i) m = fmaxf(m, v[i]);
    #pragma unroll
    for (int off = 32; off > 0; off >>= 1) m = fmaxf(m, __shfl_xor(m, off, 64));

    float s = 0.f;
    #pragma unroll
    for (int i = 0; i < 8; ++i) { v[i] = expf(v[i] - m); s += v[i]; }
    #pragma unroll
    for (int off = 32; off > 0; off >>= 1) s += __shfl_xor(s, off, 64);
    const float inv = 1.f / s;

    const int t = r >> 6, b = r & 63;
    float* dst = out + ((size_t)b * T_ + t) * E_;
    #pragma unroll
    for (int i = 0; i < 8; ++i) v[i] *= inv;
    ((float4*)dst)[lane * 2]     = *(float4*)&v[0];
    ((float4*)dst)[lane * 2 + 1] = *(float4*)&v[4];
}

// ---------------------------------------------------------------------------
extern "C" void kernel_launch(void* const* d_in, const int* in_sizes, int n_in,
                              void* d_out, int out_size, void* d_ws, size_t ws_size,
                              hipStream_t stream)
{
    const float* images   = (const float*)d_in[0];
    const int*   captions = (const int*)  d_in[1];
    const float* table    = (const float*)d_in[2];
    const float* W_ih     = (const float*)d_in[3];
    const float* W_hh     = (const float*)d_in[4];
    const float* W_hr     = (const float*)d_in[5];
    const float* b_ih     = (const float*)d_in[6];
    const float* b_hh     = (const float*)d_in[7];
    float* out = (float*)d_out;

    // Workspace layout (bytes)
    char* base = (char*)d_ws;
    float*          Xr      = (float*)base;                               // 134,217,728
    unsigned int*   bar     = (unsigned int*)(base + 134217728);          //       4,096
    unsigned short* u_ps    = (unsigned short*)(base + 134221824);        //  50,724,864
    unsigned short* WhhrPl  = (unsigned short*)(base + 184946688);        //  25,165,824
    float*          seq     = (float*)(base + 210112512);                 //  16,777,216
    // aliases (sequentially dead regions)
    float*          WhhrF32 = (float*)((char*)u_ps + 786432);
    unsigned short* WihPl   = (unsigned short*)((char*)u_ps + 786432);
    float*          logits  = Xr;
    float*          H0      = seq;

    const int SMEM_BYTES = 131072 + 3072;   // Wlds + u_sm
    (void)hipFuncSetAttribute((const void*)persistent_lstm,
                              hipFuncAttributeMaxDynamicSharedMemorySize, SMEM_BYTES);

    embed_kernel<<<T_ * B_, 128, 0, stream>>>(images, captions, table, seq);

    for (int l = 0; l < L_; ++l) {
        const float* wih = W_ih + (size_t)l * G4_ * E_;
        const float* whh = W_hh + (size_t)l * G4_ * E_;
        const float* whr = W_hr + (size_t)l * E_ * H_;
        const float* bih = b_ih + (size_t)l * G4_;
        const float* bhh = b_hh + (size_t)l * G4_;

        // Whhr = W_hh (4096,512) @ W_hr (512,1024), f32 (scratch inside u_ps)
        mfma_gemm<false><<<dim3(H_ / 128, G4_ / 128), 256, 0, stream>>>(
            whh, whr, WhhrF32, G4_, H_, E_, nullptr, nullptr);
        split_planes<<<(G4_ * H_) / 1024, 256, 0, stream>>>(WhhrF32, WhhrPl, (size_t)G4_ * H_);
        split_planes<<<(G4_ * E_) / 1024, 256, 0, stream>>>(wih, WihPl, (size_t)G4_ * E_);

        // X = inp @ W_ih^T + b_ih + b_hh, stored [t][col][b]
        const float* inp = (l == 0) ? seq : H0;
        xgemm_kernel<<<dim3(G4_ / 128, (T_ * B_) / 128), 256, 0, stream>>>(
            inp, WihPl, bih, bhh, Xr);

        // zero u(0) and barrier state
        (void)hipMemsetAsync(u_ps, 0, SLOT * sizeof(unsigned short), stream);
        (void)hipMemsetAsync(bar, 0, 4096, stream);

        // 128-step recurrence, one cooperative launch (residency guarantee)
        {
            const float* xr_a = Xr;
            const unsigned short* wpl_a = WhhrPl;
            unsigned short* ups_a = u_ps;
            unsigned int* bar_a = bar;
            void* args[] = { (void*)&xr_a, (void*)&wpl_a, (void*)&ups_a, (void*)&bar_a };
            (void)hipLaunchCooperativeKernel((const void*)persistent_lstm,
                                             dim3(128), dim3(256), args, SMEM_BYTES, stream);
        }

        // project all u -> H0 (layer 0) or logits (layer 1)
        float* pdst = (l == 0) ? H0 : logits;
        proj_gemm<<<dim3(E_ / 128, (T_ * B_) / 128), 256, 0, stream>>>(u_ps, whr, pdst);
    }

    softmax_kernel<<<(T_ * B_) / 4, 256, 0, stream>>>(logits, out);

    (void)in_sizes; (void)n_in; (void)out_size; (void)ws_size;
}

// Round 10
// 4837.780 us; speedup vs baseline: 2.3141x; 1.0965x over previous
//
#include <hip/hip_runtime.h>
#include <cstdint>
#include <cstddef>

// Problem constants
#define V_ 10000
#define E_ 512
#define H_ 1024
#define L_ 2
#define B_ 64
#define T_ 128
#define G4_ (4 * H_)                 // 4096 gate width
#define SLOT (3 * 128 * 64 * 8)      // shorts per u_ps timestep slot (3 planes)
#define PSTR 65536                   // shorts per u_ps plane (128*64*8)

typedef __attribute__((ext_vector_type(8))) short bf16x8;
typedef __attribute__((ext_vector_type(4))) float f32x4;
typedef __attribute__((ext_vector_type(4))) unsigned int u32x4;

// ---------------------------------------------------------------------------
// bf16 split helpers (RNE; finite values only)
// ---------------------------------------------------------------------------
__device__ __forceinline__ unsigned short f2b(float x) {
    unsigned u = __float_as_uint(x);
    unsigned r = (u + 0x7FFFu + ((u >> 16) & 1u)) >> 16;
    return (unsigned short)r;
}
__device__ __forceinline__ float b2f(unsigned short h) {
    return __uint_as_float(((unsigned)h) << 16);
}
__device__ __forceinline__ void split3(float a, unsigned short& h, unsigned short& l, unsigned short& q) {
    h = f2b(a); float r = a - b2f(h);
    l = f2b(r); float r2 = r - b2f(l);
    q = f2b(r2);
}

// ---------------------------------------------------------------------------
// Embedding + concat: seq (T, B, E) rows m = t*64 + b
// ---------------------------------------------------------------------------
__global__ __launch_bounds__(128) void embed_kernel(
    const float* __restrict__ images, const int* __restrict__ captions,
    const float* __restrict__ table, float* __restrict__ seq)
{
    const int m = blockIdx.x;            // 0..8191
    const int t = m >> 6, b = m & 63;
    const float* src;
    if (t == 0) src = images + (size_t)b * E_;
    else        src = table + (size_t)captions[b * T_ + (t - 1)] * E_;
    float4 v = ((const float4*)src)[threadIdx.x];
    ((float4*)(seq + (size_t)m * E_))[threadIdx.x] = v;
}

// ---------------------------------------------------------------------------
// f32 -> 3 bf16 plane split (plane stride = n elements)
// ---------------------------------------------------------------------------
__global__ __launch_bounds__(256) void split_planes(
    const float* __restrict__ in, unsigned short* __restrict__ pl, size_t n)
{
    size_t i = ((size_t)blockIdx.x * 256 + threadIdx.x) * 4;
    if (i >= n) return;
    float4 v = *(const float4*)&in[i];
    unsigned short h[4], l[4], q[4];
    split3(v.x, h[0], l[0], q[0]); split3(v.y, h[1], l[1], q[1]);
    split3(v.z, h[2], l[2], q[2]); split3(v.w, h[3], l[3], q[3]);
    ushort4 hv = {h[0], h[1], h[2], h[3]};
    ushort4 lv = {l[0], l[1], l[2], l[3]};
    ushort4 qv = {q[0], q[1], q[2], q[3]};
    *(ushort4*)&pl[i]         = hv;
    *(ushort4*)&pl[n + i]     = lv;
    *(ushort4*)&pl[2 * n + i] = qv;
}

// ---------------------------------------------------------------------------
// Split-bf16x6 MFMA GEMM, in-kernel split of both operands.
// Used only for Whhr = W_hh @ W_hr (K,N f32 B). C = A(M,K) @ B(K,N), f32 out.
// ---------------------------------------------------------------------------
template<bool BNK>
__global__ __launch_bounds__(256) void mfma_gemm(
    const float* __restrict__ A, const float* __restrict__ Bm, float* __restrict__ C,
    int M, int N, int K,
    const float* __restrict__ bias1, const float* __restrict__ bias2)
{
    __shared__ unsigned short As[3][128][40];
    __shared__ unsigned short Bs[3][128][40];
    const int bm = blockIdx.y * 128, bn = blockIdx.x * 128;
    const int tid = threadIdx.x;
    const int lane = tid & 63, wid = tid >> 6;
    const int wm = wid >> 1, wn = wid & 1;
    const int lr = lane & 15, lk = (lane >> 4) * 8;

    f32x4 acc[4][4] = {};

    for (int k0 = 0; k0 < K; k0 += 32) {
        #pragma unroll
        for (int p = 0; p < 4; ++p) {
            int flat = p * 256 + tid;
            int c4 = flat & 7, r = flat >> 3;
            float4 v = *(const float4*)&A[(size_t)(bm + r) * K + k0 + c4 * 4];
            unsigned short h[4], l[4], q[4];
            split3(v.x, h[0], l[0], q[0]); split3(v.y, h[1], l[1], q[1]);
            split3(v.z, h[2], l[2], q[2]); split3(v.w, h[3], l[3], q[3]);
            unsigned* dh = (unsigned*)&As[0][r][c4 * 4];
            dh[0] = h[0] | ((unsigned)h[1] << 16); dh[1] = h[2] | ((unsigned)h[3] << 16);
            unsigned* dl = (unsigned*)&As[1][r][c4 * 4];
            dl[0] = l[0] | ((unsigned)l[1] << 16); dl[1] = l[2] | ((unsigned)l[3] << 16);
            unsigned* dq = (unsigned*)&As[2][r][c4 * 4];
            dq[0] = q[0] | ((unsigned)q[1] << 16); dq[1] = q[2] | ((unsigned)q[3] << 16);
        }
        if (BNK) {
            #pragma unroll
            for (int p = 0; p < 4; ++p) {
                int flat = p * 256 + tid;
                int c4 = flat & 7, r = flat >> 3;
                float4 v = *(const float4*)&Bm[(size_t)(bn + r) * K + k0 + c4 * 4];
                unsigned short h[4], l[4], q[4];
                split3(v.x, h[0], l[0], q[0]); split3(v.y, h[1], l[1], q[1]);
                split3(v.z, h[2], l[2], q[2]); split3(v.w, h[3], l[3], q[3]);
                unsigned* dh = (unsigned*)&Bs[0][r][c4 * 4];
                dh[0] = h[0] | ((unsigned)h[1] << 16); dh[1] = h[2] | ((unsigned)h[3] << 16);
                unsigned* dl = (unsigned*)&Bs[1][r][c4 * 4];
                dl[0] = l[0] | ((unsigned)l[1] << 16); dl[1] = l[2] | ((unsigned)l[3] << 16);
                unsigned* dq = (unsigned*)&Bs[2][r][c4 * 4];
                dq[0] = q[0] | ((unsigned)q[1] << 16); dq[1] = q[2] | ((unsigned)q[3] << 16);
            }
        } else {
            #pragma unroll
            for (int p = 0; p < 4; ++p) {
                int flat = p * 256 + tid;
                int n4 = flat & 31, kr = flat >> 5;
                float4 v = *(const float4*)&Bm[(size_t)(k0 + kr) * N + bn + n4 * 4];
                float vv[4] = {v.x, v.y, v.z, v.w};
                #pragma unroll
                for (int jj = 0; jj < 4; ++jj) {
                    unsigned short h, l, q; split3(vv[jj], h, l, q);
                    Bs[0][n4 * 4 + jj][kr] = h;
                    Bs[1][n4 * 4 + jj][kr] = l;
                    Bs[2][n4 * 4 + jj][kr] = q;
                }
            }
        }
        __syncthreads();

        bf16x8 af[3][4], bf[3][4];
        #pragma unroll
        for (int pl = 0; pl < 3; ++pl)
            #pragma unroll
            for (int m = 0; m < 4; ++m) {
                af[pl][m] = *(const bf16x8*)&As[pl][wm * 64 + m * 16 + lr][lk];
                bf[pl][m] = *(const bf16x8*)&Bs[pl][wn * 64 + m * 16 + lr][lk];
            }
        #pragma unroll
        for (int m = 0; m < 4; ++m)
            #pragma unroll
            for (int n = 0; n < 4; ++n) {
                acc[m][n] = __builtin_amdgcn_mfma_f32_16x16x32_bf16(af[0][m], bf[0][n], acc[m][n], 0, 0, 0);
                acc[m][n] = __builtin_amdgcn_mfma_f32_16x16x32_bf16(af[0][m], bf[1][n], acc[m][n], 0, 0, 0);
                acc[m][n] = __builtin_amdgcn_mfma_f32_16x16x32_bf16(af[1][m], bf[0][n], acc[m][n], 0, 0, 0);
                acc[m][n] = __builtin_amdgcn_mfma_f32_16x16x32_bf16(af[1][m], bf[1][n], acc[m][n], 0, 0, 0);
                acc[m][n] = __builtin_amdgcn_mfma_f32_16x16x32_bf16(af[0][m], bf[2][n], acc[m][n], 0, 0, 0);
                acc[m][n] = __builtin_amdgcn_mfma_f32_16x16x32_bf16(af[2][m], bf[0][n], acc[m][n], 0, 0, 0);
            }
        __syncthreads();
    }

    float bv[4];
    #pragma unroll
    for (int n = 0; n < 4; ++n) {
        int col = bn + wn * 64 + n * 16 + lr;
        float x = 0.f;
        if (bias1) x += bias1[col];
        if (bias2) x += bias2[col];
        bv[n] = x;
    }
    #pragma unroll
    for (int m = 0; m < 4; ++m) {
        int rbase = bm + wm * 64 + m * 16 + (lane >> 4) * 4;
        #pragma unroll
        for (int n = 0; n < 4; ++n) {
            int col = bn + wn * 64 + n * 16 + lr;
            #pragma unroll
            for (int r = 0; r < 4; ++r)
                C[(size_t)(rbase + r) * N + col] = acc[m][n][r] + bv[n];
        }
    }
}

// ---------------------------------------------------------------------------
// X GEMM: Xr[t][col][b] = (seq/H0)(8192,512) @ W_ih^T + b_ih + b_hh
// ---------------------------------------------------------------------------
__global__ __launch_bounds__(256) void xgemm_kernel(
    const float* __restrict__ A, const unsigned short* __restrict__ Bpl,
    const float* __restrict__ bias1, const float* __restrict__ bias2,
    float* __restrict__ Xr)
{
    __shared__ unsigned short As[3][128][40];
    __shared__ unsigned short Bs[3][128][40];
    const int bm = blockIdx.y * 128, bn = blockIdx.x * 128;
    const int tid = threadIdx.x;
    const int lane = tid & 63, wid = tid >> 6;
    const int wm = wid >> 1, wn = wid & 1;
    const int lr = lane & 15, lg = lane >> 4, lk = lg * 8;

    f32x4 acc[4][4] = {};

    for (int k0 = 0; k0 < E_; k0 += 32) {
        #pragma unroll
        for (int p = 0; p < 4; ++p) {
            int flat = p * 256 + tid;
            int c4 = flat & 7, r = flat >> 3;
            float4 v = *(const float4*)&A[(size_t)(bm + r) * E_ + k0 + c4 * 4];
            unsigned short h[4], l[4], q[4];
            split3(v.x, h[0], l[0], q[0]); split3(v.y, h[1], l[1], q[1]);
            split3(v.z, h[2], l[2], q[2]); split3(v.w, h[3], l[3], q[3]);
            unsigned* dh = (unsigned*)&As[0][r][c4 * 4];
            dh[0] = h[0] | ((unsigned)h[1] << 16); dh[1] = h[2] | ((unsigned)h[3] << 16);
            unsigned* dl = (unsigned*)&As[1][r][c4 * 4];
            dl[0] = l[0] | ((unsigned)l[1] << 16); dl[1] = l[2] | ((unsigned)l[3] << 16);
            unsigned* dq = (unsigned*)&As[2][r][c4 * 4];
            dq[0] = q[0] | ((unsigned)q[1] << 16); dq[1] = q[2] | ((unsigned)q[3] << 16);
        }
        #pragma unroll
        for (int p6 = 0; p6 < 6; ++p6) {
            int f = p6 * 256 + tid;
            int pl = f >> 9, rem = f & 511;
            int r = rem >> 2, g4 = rem & 3;
            const unsigned short* src = Bpl + (size_t)pl * (G4_ * E_) + (size_t)(bn + r) * E_ + k0 + g4 * 8;
            *(uint4*)&Bs[pl][r][g4 * 8] = *(const uint4*)src;
        }
        __syncthreads();

        bf16x8 af[3][4], bf[3][4];
        #pragma unroll
        for (int pl = 0; pl < 3; ++pl)
            #pragma unroll
            for (int m = 0; m < 4; ++m) {
                af[pl][m] = *(const bf16x8*)&As[pl][wm * 64 + m * 16 + lr][lk];
                bf[pl][m] = *(const bf16x8*)&Bs[pl][wn * 64 + m * 16 + lr][lk];
            }
        #pragma unroll
        for (int m = 0; m < 4; ++m)
            #pragma unroll
            for (int n = 0; n < 4; ++n) {
                acc[m][n] = __builtin_amdgcn_mfma_f32_16x16x32_bf16(af[0][m], bf[0][n], acc[m][n], 0, 0, 0);
                acc[m][n] = __builtin_amdgcn_mfma_f32_16x16x32_bf16(af[0][m], bf[1][n], acc[m][n], 0, 0, 0);
                acc[m][n] = __builtin_amdgcn_mfma_f32_16x16x32_bf16(af[1][m], bf[0][n], acc[m][n], 0, 0, 0);
                acc[m][n] = __builtin_amdgcn_mfma_f32_16x16x32_bf16(af[1][m], bf[1][n], acc[m][n], 0, 0, 0);
                acc[m][n] = __builtin_amdgcn_mfma_f32_16x16x32_bf16(af[0][m], bf[2][n], acc[m][n], 0, 0, 0);
                acc[m][n] = __builtin_amdgcn_mfma_f32_16x16x32_bf16(af[2][m], bf[0][n], acc[m][n], 0, 0, 0);
            }
        __syncthreads();
    }

    #pragma unroll
    for (int n = 0; n < 4; ++n) {
        int col = bn + wn * 64 + n * 16 + lr;
        float bv = bias1[col] + bias2[col];
        #pragma unroll
        for (int m = 0; m < 4; ++m) {
            int rbase = bm + wm * 64 + m * 16 + lg * 4;
            #pragma unroll
            for (int r = 0; r < 4; ++r) {
                int row = rbase + r;
                Xr[((size_t)(row >> 6) * G4_ + col) * 64 + (row & 63)] = acc[m][n][r] + bv;
            }
        }
    }
}

// ---------------------------------------------------------------------------
// Persistent 128-step LSTM recurrence, 128 blocks x 8 hcols x 512 threads.
// R10: TLP latency hiding — 8 waves/block, K split in half across wave
// groups (waves 0-3: k<512, waves 4-7: k>=512), partials combined in LDS.
// Per-wave k-loop is R7's EXACT serial form (proven ordering; the R8/R9
// register-prefetch variant raced). Coherence scheme: R7-proven
// (sc0sc1 write-through u stores + vmcnt drain; relaxed direct-poll
// barrier, 32 counters, monotone targets; normal cached consumer loads).
// ---------------------------------------------------------------------------
__global__ __launch_bounds__(512, 1) void persistent_lstm(
    const float* __restrict__ Xr,              // [128][4096][64]
    const unsigned short* __restrict__ Wpl,    // [3][4096*1024]
    unsigned short* __restrict__ u_ps,         // [129][SLOT]
    unsigned int* bar)                         // 32 counters, 64B apart
{
    extern __shared__ unsigned short smem[];
    unsigned short* Wlds = smem;               // [2pl][2h2][16n][1024] = 131072 B
    unsigned short* u_sm = smem + 65536;       // [3][64][8] shorts = 3072 B
    float* psum = (float*)(smem + 67072);      // [4bq][64lane][8] floats = 8192 B

    const int tid = threadIdx.x;
    const int j = blockIdx.x;                  // 0..127
    const int wid = tid >> 6, lane = tid & 63;
    const int half = wid >> 2, bq = wid & 3;
    const int lr = lane & 15, lg = lane >> 4;

    // stage hi/lo planes of this block's 32 gate-rows (2 tiles x 16 rows)
    for (int it = 0; it < 16; ++it) {
        int f = it * 512 + tid;                // 0..8191 16B-chunks
        int p = f >> 12;
        int rem = f & 4095;
        int h2 = rem >> 11;
        int rem2 = rem & 2047;
        int n = rem2 >> 7;                     // 0..15
        int g16 = rem2 & 127;                  // 0..127
        int gr = (n & 3) * 1024 + j * 8 + h2 * 4 + (n >> 2);
        const unsigned short* src = Wpl + (size_t)p * (G4_ * H_) + (size_t)gr * H_ + g16 * 8;
        *(uint4*)&Wlds[(size_t)((p * 2 + h2) * 16 + n) * 1024 + (g16 ^ (n & 7)) * 8] = *(const uint4*)src;
    }
    __syncthreads();

    const int b = bq * 16 + lr;
    const int uoff = b * 8;
    const int swzb = lr & 7;
    const int kbase = half * 64;               // g16 offset for this wave group
    const unsigned short* wq0 = Wpl + (size_t)2 * (G4_ * H_)
        + (size_t)((lr & 3) * 1024 + j * 8 + 0 + (lr >> 2)) * H_;
    const unsigned short* wq1 = Wpl + (size_t)2 * (G4_ * H_)
        + (size_t)((lr & 3) * 1024 + j * 8 + 4 + (lr >> 2)) * H_;

    float c0 = 0.f, c1 = 0.f;

    for (int t = 0; t < T_; ++t) {
        const unsigned short* ut = u_ps + (size_t)t * SLOT;
        float xg0[4], xg1[4];
        if (half == 0) {
            #pragma unroll
            for (int g = 0; g < 4; ++g) {
                xg0[g] = Xr[((size_t)t * G4_ + g * 1024 + j * 8 + lg) * 64 + b];
                xg1[g] = Xr[((size_t)t * G4_ + g * 1024 + j * 8 + 4 + lg) * 64 + b];
            }
        }

        f32x4 a0 = {0.f, 0.f, 0.f, 0.f}, p0 = {0.f, 0.f, 0.f, 0.f};
        f32x4 a1 = {0.f, 0.f, 0.f, 0.f}, p1 = {0.f, 0.f, 0.f, 0.f};
        // R7-exact serial k-loop over this wave group's half of K (16 ks)
        #pragma unroll 8
        for (int ks = 0; ks < 16; ++ks) {
            int g16 = kbase + ks * 4 + lg;
            int swz = (g16 ^ swzb) * 8;
            bf16x8 uh = *(const bf16x8*)&ut[(size_t)g16 * 512 + uoff];
            bf16x8 ul = *(const bf16x8*)&ut[PSTR + (size_t)g16 * 512 + uoff];
            bf16x8 uq = *(const bf16x8*)&ut[2 * PSTR + (size_t)g16 * 512 + uoff];
            bf16x8 wh0 = *(const bf16x8*)&Wlds[(size_t)(0 * 16 + lr) * 1024 + swz];
            bf16x8 wh1 = *(const bf16x8*)&Wlds[(size_t)(1 * 16 + lr) * 1024 + swz];
            bf16x8 wl0 = *(const bf16x8*)&Wlds[(size_t)(2 * 16 + lr) * 1024 + swz];
            bf16x8 wl1 = *(const bf16x8*)&Wlds[(size_t)(3 * 16 + lr) * 1024 + swz];
            bf16x8 wq0v = *(const bf16x8*)&wq0[g16 * 8];
            bf16x8 wq1v = *(const bf16x8*)&wq1[g16 * 8];
            a0 = __builtin_amdgcn_mfma_f32_16x16x32_bf16(wh0, uh, a0, 0, 0, 0);
            a0 = __builtin_amdgcn_mfma_f32_16x16x32_bf16(wh0, ul, a0, 0, 0, 0);
            a0 = __builtin_amdgcn_mfma_f32_16x16x32_bf16(wl0, uh, a0, 0, 0, 0);
            p0 = __builtin_amdgcn_mfma_f32_16x16x32_bf16(wl0, ul, p0, 0, 0, 0);
            p0 = __builtin_amdgcn_mfma_f32_16x16x32_bf16(wh0, uq, p0, 0, 0, 0);
            p0 = __builtin_amdgcn_mfma_f32_16x16x32_bf16(wq0v, uh, p0, 0, 0, 0);
            a1 = __builtin_amdgcn_mfma_f32_16x16x32_bf16(wh1, uh, a1, 0, 0, 0);
            a1 = __builtin_amdgcn_mfma_f32_16x16x32_bf16(wh1, ul, a1, 0, 0, 0);
            a1 = __builtin_amdgcn_mfma_f32_16x16x32_bf16(wl1, uh, a1, 0, 0, 0);
            p1 = __builtin_amdgcn_mfma_f32_16x16x32_bf16(wl1, ul, p1, 0, 0, 0);
            p1 = __builtin_amdgcn_mfma_f32_16x16x32_bf16(wh1, uq, p1, 0, 0, 0);
            p1 = __builtin_amdgcn_mfma_f32_16x16x32_bf16(wq1v, uh, p1, 0, 0, 0);
        }

        // combine k-halves: upper waves publish partials, lower waves consume
        if (half == 1) {
            f32x4 s0 = a0 + p0;
            f32x4 s1 = a1 + p1;
            float* pp = &psum[(size_t)(bq * 64 + lane) * 8];
            *(f32x4*)&pp[0] = s0;
            *(f32x4*)&pp[4] = s1;
        }
        __syncthreads();                       // partials visible

        if (half == 0) {
            const float* pp = &psum[(size_t)(bq * 64 + lane) * 8];
            f32x4 s0o = *(const f32x4*)&pp[0];
            f32x4 s1o = *(const f32x4*)&pp[4];
            {   // tile 0: hcol = j*8 + lg
                float gi = a0[0] + p0[0] + s0o[0] + xg0[0];
                float gf = a0[1] + p0[1] + s0o[1] + xg0[1];
                float gv = a0[2] + p0[2] + s0o[2] + xg0[2];
                float go = a0[3] + p0[3] + s0o[3] + xg0[3];
                float si = 1.f / (1.f + __expf(-gi));
                float sf = 1.f / (1.f + __expf(-gf));
                float so = 1.f / (1.f + __expf(-go));
                c0 = sf * c0 + si * tanhf(gv);
                float ho = so * tanhf(c0);
                unsigned short sh, sl, sq;
                split3(ho, sh, sl, sq);
                u_sm[(0 * 64 + b) * 8 + lg] = sh;
                u_sm[(1 * 64 + b) * 8 + lg] = sl;
                u_sm[(2 * 64 + b) * 8 + lg] = sq;
            }
            {   // tile 1: hcol = j*8 + 4 + lg
                float gi = a1[0] + p1[0] + s1o[0] + xg1[0];
                float gf = a1[1] + p1[1] + s1o[1] + xg1[1];
                float gv = a1[2] + p1[2] + s1o[2] + xg1[2];
                float go = a1[3] + p1[3] + s1o[3] + xg1[3];
                float si = 1.f / (1.f + __expf(-gi));
                float sf = 1.f / (1.f + __expf(-gf));
                float so = 1.f / (1.f + __expf(-go));
                c1 = sf * c1 + si * tanhf(gv);
                float ho = so * tanhf(c1);
                unsigned short sh, sl, sq;
                split3(ho, sh, sl, sq);
                u_sm[(0 * 64 + b) * 8 + 4 + lg] = sh;
                u_sm[(1 * 64 + b) * 8 + 4 + lg] = sl;
                u_sm[(2 * 64 + b) * 8 + 4 + lg] = sq;
            }
        }
        __syncthreads();                       // u_sm complete

        if (tid < 192) {                       // 3 planes x 64 batches
            int pl = tid >> 6, bb = tid & 63;
            u32x4 v = *(const u32x4*)&u_sm[(pl * 64 + bb) * 8];
            unsigned short* dst = u_ps + (size_t)(t + 1) * SLOT
                                + (size_t)pl * PSTR + (size_t)(j * 64 + bb) * 8;
            asm volatile("global_store_dwordx4 %0, %1, off sc0 sc1"
                         :: "v"(dst), "v"(v) : "memory");
        }
        asm volatile("s_waitcnt vmcnt(0)" ::: "memory");
        __syncthreads();                       // all waves' stores drained

        if (t != T_ - 1) {
            // R7-proven direct-poll barrier
            if (tid == 0)
                __hip_atomic_fetch_add(&bar[(j & 31) * 16], 1u,
                                       __ATOMIC_RELAXED, __HIP_MEMORY_SCOPE_AGENT);
            if (tid < 32) {
                const unsigned tgt = (unsigned)(t + 1) * 4u;
                while (__hip_atomic_load(&bar[tid * 16],
                                         __ATOMIC_RELAXED, __HIP_MEMORY_SCOPE_AGENT) < tgt) {}
            }
            __syncthreads();
        }
    }
}

// ---------------------------------------------------------------------------
// Projection GEMM: C(8192,512) = U(8192,1024) @ W_hr^T
// ---------------------------------------------------------------------------
__global__ __launch_bounds__(256) void proj_gemm(
    const unsigned short* __restrict__ u_ps,   // [129][SLOT]
    const float* __restrict__ Whr,             // (512,1024) f32 (N,K)
    float* __restrict__ C)                     // (8192,512)
{
    __shared__ unsigned short Bs[3][128][40];
    const int bn = blockIdx.x * 128;
    const int bm = blockIdx.y * 128;
    const int tid = threadIdx.x;
    const int lane = tid & 63, wid = tid >> 6;
    const int wm = wid >> 1, wn = wid & 1;
    const int lr = lane & 15, lg = lane >> 4, lk = lg * 8;

    f32x4 acc[4][4] = {};
    const int t = (bm >> 6) + wm;
    const unsigned short* ut = u_ps + (size_t)(t + 1) * SLOT;

    for (int k0 = 0; k0 < H_; k0 += 32) {
        #pragma unroll
        for (int p = 0; p < 4; ++p) {
            int flat = p * 256 + tid;
            int c4 = flat & 7, r = flat >> 3;
            float4 v = *(const float4*)&Whr[(size_t)(bn + r) * H_ + k0 + c4 * 4];
            unsigned short h[4], l[4], q[4];
            split3(v.x, h[0], l[0], q[0]); split3(v.y, h[1], l[1], q[1]);
            split3(v.z, h[2], l[2], q[2]); split3(v.w, h[3], l[3], q[3]);
            unsigned* dh = (unsigned*)&Bs[0][r][c4 * 4];
            dh[0] = h[0] | ((unsigned)h[1] << 16); dh[1] = h[2] | ((unsigned)h[3] << 16);
            unsigned* dl = (unsigned*)&Bs[1][r][c4 * 4];
            dl[0] = l[0] | ((unsigned)l[1] << 16); dl[1] = l[2] | ((unsigned)l[3] << 16);
            unsigned* dq = (unsigned*)&Bs[2][r][c4 * 4];
            dq[0] = q[0] | ((unsigned)q[1] << 16); dq[1] = q[2] | ((unsigned)q[3] << 16);
        }
        __syncthreads();

        int ks = k0 >> 5;
        bf16x8 af[3][4], bf[3][4];
        #pragma unroll
        for (int pl = 0; pl < 3; ++pl)
            #pragma unroll
            for (int m = 0; m < 4; ++m) {
                af[pl][m] = *(const bf16x8*)&ut[(size_t)pl * PSTR + (size_t)((ks * 4 + lg) * 64 + m * 16 + lr) * 8];
                bf[pl][m] = *(const bf16x8*)&Bs[pl][wn * 64 + m * 16 + lr][lk];
            }
        #pragma unroll
        for (int m = 0; m < 4; ++m)
            #pragma unroll
            for (int n = 0; n < 4; ++n) {
                acc[m][n] = __builtin_amdgcn_mfma_f32_16x16x32_bf16(af[0][m], bf[0][n], acc[m][n], 0, 0, 0);
                acc[m][n] = __builtin_amdgcn_mfma_f32_16x16x32_bf16(af[0][m], bf[1][n], acc[m][n], 0, 0, 0);
                acc[m][n] = __builtin_amdgcn_mfma_f32_16x16x32_bf16(af[1][m], bf[0][n], acc[m][n], 0, 0, 0);
                acc[m][n] = __builtin_amdgcn_mfma_f32_16x16x32_bf16(af[1][m], bf[1][n], acc[m][n], 0, 0, 0);
                acc[m][n] = __builtin_amdgcn_mfma_f32_16x16x32_bf16(af[0][m], bf[2][n], acc[m][n], 0, 0, 0);
                acc[m][n] = __builtin_amdgcn_mfma_f32_16x16x32_bf16(af[2][m], bf[0][n], acc[m][n], 0, 0, 0);
            }
        __syncthreads();
    }

    #pragma unroll
    for (int m = 0; m < 4; ++m) {
        int rbase = bm + wm * 64 + m * 16 + lg * 4;
        #pragma unroll
        for (int n = 0; n < 4; ++n) {
            int col = bn + wn * 64 + n * 16 + lr;
            #pragma unroll
            for (int r = 0; r < 4; ++r)
                C[(size_t)(rbase + r) * E_ + col] = acc[m][n][r];
        }
    }
}

// ---------------------------------------------------------------------------
// Row softmax over E=512; input rows m = t*64+b, output row (b, t).
// ---------------------------------------------------------------------------
__global__ __launch_bounds__(256) void softmax_kernel(
    const float* __restrict__ LOG, float* __restrict__ out)
{
    const int lane = threadIdx.x & 63;
    const int r = blockIdx.x * 4 + (threadIdx.x >> 6);
    const float* src = LOG + (size_t)r * E_;
    float v[8];
    *(float4*)&v[0] = ((const float4*)src)[lane * 2];
    *(float4*)&v[4] = ((const float4*)src)[lane * 2 + 1];

    float m = v[0];
    #pragma unroll
    for (int i = 1; i < 8; ++i) m = fmaxf(m, v[i]);
    #pragma unroll
    for (int off = 32; off > 0; off >>= 1) m = fmaxf(m, __shfl_xor(m, off, 64));

    float s = 0.f;
    #pragma unroll
    for (int i = 0; i < 8; ++i) { v[i] = expf(v[i] - m); s += v[i]; }
    #pragma unroll
    for (int off = 32; off > 0; off >>= 1) s += __shfl_xor(s, off, 64);
    const float inv = 1.f / s;

    const int t = r >> 6, b = r & 63;
    float* dst = out + ((size_t)b * T_ + t) * E_;
    #pragma unroll
    for (int i = 0; i < 8; ++i) v[i] *= inv;
    ((float4*)dst)[lane * 2]     = *(float4*)&v[0];
    ((float4*)dst)[lane * 2 + 1] = *(float4*)&v[4];
}

// ---------------------------------------------------------------------------
extern "C" void kernel_launch(void* const* d_in, const int* in_sizes, int n_in,
                              void* d_out, int out_size, void* d_ws, size_t ws_size,
                              hipStream_t stream)
{
    const float* images   = (const float*)d_in[0];
    const int*   captions = (const int*)  d_in[1];
    const float* table    = (const float*)d_in[2];
    const float* W_ih     = (const float*)d_in[3];
    const float* W_hh     = (const float*)d_in[4];
    const float* W_hr     = (const float*)d_in[5];
    const float* b_ih     = (const float*)d_in[6];
    const float* b_hh     = (const float*)d_in[7];
    float* out = (float*)d_out;

    // Workspace layout (bytes)
    char* base = (char*)d_ws;
    float*          Xr      = (float*)base;                               // 134,217,728
    unsigned int*   bar     = (unsigned int*)(base + 134217728);          //       4,096
    unsigned short* u_ps    = (unsigned short*)(base + 134221824);        //  50,724,864
    unsigned short* WhhrPl  = (unsigned short*)(base + 184946688);        //  25,165,824
    float*          seq     = (float*)(base + 210112512);                 //  16,777,216
    // aliases (sequentially dead regions)
    float*          WhhrF32 = (float*)((char*)u_ps + 786432);
    unsigned short* WihPl   = (unsigned short*)((char*)u_ps + 786432);
    float*          logits  = Xr;
    float*          H0      = seq;

    const int SMEM_BYTES = 131072 + 3072 + 8192;   // Wlds + u_sm + psum
    (void)hipFuncSetAttribute((const void*)persistent_lstm,
                              hipFuncAttributeMaxDynamicSharedMemorySize, SMEM_BYTES);

    embed_kernel<<<T_ * B_, 128, 0, stream>>>(images, captions, table, seq);

    for (int l = 0; l < L_; ++l) {
        const float* wih = W_ih + (size_t)l * G4_ * E_;
        const float* whh = W_hh + (size_t)l * G4_ * E_;
        const float* whr = W_hr + (size_t)l * E_ * H_;
        const float* bih = b_ih + (size_t)l * G4_;
        const float* bhh = b_hh + (size_t)l * G4_;

        // Whhr = W_hh (4096,512) @ W_hr (512,1024), f32 (scratch inside u_ps)
        mfma_gemm<false><<<dim3(H_ / 128, G4_ / 128), 256, 0, stream>>>(
            whh, whr, WhhrF32, G4_, H_, E_, nullptr, nullptr);
        split_planes<<<(G4_ * H_) / 1024, 256, 0, stream>>>(WhhrF32, WhhrPl, (size_t)G4_ * H_);
        split_planes<<<(G4_ * E_) / 1024, 256, 0, stream>>>(wih, WihPl, (size_t)G4_ * E_);

        // X = inp @ W_ih^T + b_ih + b_hh, stored [t][col][b]
        const float* inp = (l == 0) ? seq : H0;
        xgemm_kernel<<<dim3(G4_ / 128, (T_ * B_) / 128), 256, 0, stream>>>(
            inp, WihPl, bih, bhh, Xr);

        // zero u(0) and barrier state
        (void)hipMemsetAsync(u_ps, 0, SLOT * sizeof(unsigned short), stream);
        (void)hipMemsetAsync(bar, 0, 4096, stream);

        // 128-step recurrence, one cooperative launch (residency guarantee)
        {
            const float* xr_a = Xr;
            const unsigned short* wpl_a = WhhrPl;
            unsigned short* ups_a = u_ps;
            unsigned int* bar_a = bar;
            void* args[] = { (void*)&xr_a, (void*)&wpl_a, (void*)&ups_a, (void*)&bar_a };
            (void)hipLaunchCooperativeKernel((const void*)persistent_lstm,
                                             dim3(128), dim3(512), args, SMEM_BYTES, stream);
        }

        // project all u -> H0 (layer 0) or logits (layer 1)
        float* pdst = (l == 0) ? H0 : logits;
        proj_gemm<<<dim3(E_ / 128, (T_ * B_) / 128), 256, 0, stream>>>(u_ps, whr, pdst);
    }

    softmax_kernel<<<(T_ * B_) / 4, 256, 0, stream>>>(logits, out);

    (void)in_sizes; (void)n_in; (void)out_size; (void)ws_size;
}